// Round 9
// baseline (713.880 us; speedup 1.0000x reference)
//
#include <hip/hip_runtime.h>

typedef __attribute__((ext_vector_type(8))) short bf16x8;
typedef __attribute__((ext_vector_type(8))) unsigned short u16x8;
typedef __attribute__((ext_vector_type(4))) unsigned short u16x4;
typedef __attribute__((ext_vector_type(4))) float f32x4;
typedef __attribute__((ext_vector_type(2))) unsigned uint2v;

#define DEV static __device__ __forceinline__

DEV unsigned short f2bf(float f){
  unsigned u = __float_as_uint(f);
  u += 0x7fff + ((u>>16)&1);
  return (unsigned short)(u>>16);
}
DEV float bf2f(unsigned short b){ return __uint_as_float(((unsigned)b)<<16); }
DEV unsigned cvtpk(float lo, float hi){
  unsigned r;
  asm("v_cvt_pk_bf16_f32 %0, %1, %2" : "=v"(r) : "v"(lo), "v"(hi));
  return r;
}

DEV void gll16(const void* g, void* l){
  __builtin_amdgcn_global_load_lds((__attribute__((address_space(1))) unsigned*)(void*)g,
                                   (__attribute__((address_space(3))) unsigned*)l, 16, 0, 0);
}

// ---------------- cast fp32 -> bf16 (vectorized) ----------------
__global__ void k_cast(const float* __restrict__ x, unsigned short* __restrict__ y, int n4){
  int i = blockIdx.x*256 + threadIdx.x;
  if (i >= n4) return;
  f32x4 v = ((const f32x4*)x)[i];
  u16x4 o = { f2bf(v.x), f2bf(v.y), f2bf(v.z), f2bf(v.w) };
  ((u16x4*)y)[i] = o;
}

// ---------------- 6-segment weight cast ----------------
__global__ void k_castW(const float* __restrict__ s0, const float* __restrict__ s1,
                        const float* __restrict__ s2, const float* __restrict__ s3,
                        const float* __restrict__ s4, const float* __restrict__ s5,
                        unsigned short* __restrict__ y){
  unsigned i = blockIdx.x*256 + threadIdx.x;          // < 6*2359296
  unsigned seg = i / 2359296u;
  unsigned off = i - seg*2359296u;
  const float* s = seg==0?s0: seg==1?s1: seg==2?s2: seg==3?s3: seg==4?s4: s5;
  f32x4 v = ((const f32x4*)s)[off];
  u16x4 o = { f2bf(v.x), f2bf(v.y), f2bf(v.z), f2bf(v.w) };
  ((u16x4*)y)[i] = o;
}

// ---------------- 2-segment weight cast (wo/wao) ----------------
__global__ void k_castW2(const float* __restrict__ s0, const float* __restrict__ s1,
                         unsigned short* __restrict__ y){
  unsigned i = blockIdx.x*256 + threadIdx.x;          // < 2*2359296
  unsigned seg = i / 2359296u;
  unsigned off = i - seg*2359296u;
  const float* s = seg==0?s0:s1;
  f32x4 v = ((const f32x4*)s)[off];
  u16x4 o = { f2bf(v.x), f2bf(v.y), f2bf(v.z), f2bf(v.w) };
  ((u16x4*)y)[i] = o;
}

// ---------------- QKV projection GEMM, fully fused epilogues ----------------
// sec0 (Q): RMS(nq)+RoPE(qsc) -> Qd ; sec1 (K): RMS(nk)+RoPE -> Kd ;
// sec2 (V): 2-pass LDS-transpose -> Vd[(b,)h][d][tok] (SH stays 32 KB -> 5 blocks/CU).
// Swizzle: slot ^= (row&3) ^ 2*((row>>3)&1)  (2-way residual conflict = free).
__global__ __launch_bounds__(256, 5) void k_gemmP(
    const unsigned short* __restrict__ X, const unsigned short* __restrict__ W,
    const float* __restrict__ b0, const float* __restrict__ b1, const float* __restrict__ b2,
    const float* __restrict__ nqw, const float* __restrict__ nkw,
    const float* __restrict__ cs, const float* __restrict__ sn,
    unsigned short* __restrict__ Qd, unsigned short* __restrict__ Kd,
    unsigned short* __restrict__ Vd,
    int is_img)
{
  const int K = 3072;
  __shared__ unsigned short SH[16384];                // exactly 32768 B
  unsigned short (*As)[4096] = (unsigned short(*)[4096])SH;
  unsigned short (*Bs)[4096] = (unsigned short(*)[4096])(SH + 8192);
  const int t = threadIdx.x, w = t>>6, l = t&63;
  const int li = l&15, g = l>>4;
  const int by = blockIdx.y, bx = blockIdx.x;
  const int sec = by>=48 ? 2 : (by>=24 ? 1 : 0);
  const int hd = by - sec*24;
  const int Cl = hd*128;
  const int R = bx*128;
  const unsigned short* Wp = W + (long)sec*9437184 + (long)Cl*K;
  const float* bias = (sec==0)?b0:(sec==1)?b1:b2;
  const int wr = w>>1, wc = w&1;
  f32x4 acc[4][4] = {};

  auto stage = [&](int buf, int kt){
    const int k0 = kt*32;
    #pragma unroll
    for (int c=0;c<2;c++){
      int row = c*64 + (t>>2);
      int scol = ((t&3)<<3) ^ ((row&3)<<3) ^ (((row>>3)&1)<<4);
      gll16(X + (long)(R+row)*K + k0 + scol, &As[buf][c*2048 + w*512]);
      gll16(Wp + (long)row*K + k0 + scol, &Bs[buf][c*2048 + w*512]);
    }
  };

  stage(0,0);
  int buf = 0;
  for (int kt=0; kt<96; kt++){
    __syncthreads();
    if (kt+1 < 96) stage(buf^1, kt+1);
    bf16x8 a[4], b[4];
    #pragma unroll
    for (int m=0;m<4;m++){
      int ar = wr*64 + m*16 + li;
      int ac = (g<<3) ^ ((ar&3)<<3) ^ (((ar>>3)&1)<<4);
      a[m] = *(const bf16x8*)&As[buf][ar*32 + ac];
      int br = wc*64 + m*16 + li;
      int bc2 = (g<<3) ^ ((br&3)<<3) ^ (((br>>3)&1)<<4);
      b[m] = *(const bf16x8*)&Bs[buf][br*32 + bc2];
    }
    #pragma unroll
    for (int m=0;m<4;m++)
      #pragma unroll
      for (int n=0;n<4;n++)
        acc[m][n] = __builtin_amdgcn_mfma_f32_16x16x32_bf16(a[m], b[n], acc[m][n], 0,0,0);
    buf ^= 1;
  }

  float bias_n[4];
  #pragma unroll
  for (int n=0;n<4;n++) bias_n[n] = bias[Cl + wc*64 + n*16 + li];

  if (sec == 2){
    // ---- V: 2-pass LDS-transpose epilogue (SHT[64 d][136 tok]) ----
    unsigned short* SHT = SH;
    #pragma unroll
    for (int pass=0; pass<2; pass++){
      __syncthreads();                               // staging / prev-pass reads done
      if (wc == pass){
        #pragma unroll
        for (int m=0;m<4;m++){
          int tok_l = wr*64 + m*16 + (g<<2);
          #pragma unroll
          for (int n=0;n<4;n++){
            int col_loc = n*16 + li;                 // 0..63 within this pass
            u16x4 v4 = { f2bf(acc[m][n][0]+bias_n[n]), f2bf(acc[m][n][1]+bias_n[n]),
                         f2bf(acc[m][n][2]+bias_n[n]), f2bf(acc[m][n][3]+bias_n[n]) };
            *(u16x4*)&SHT[col_loc*136 + tok_l] = v4;
          }
        }
      }
      __syncthreads();
      int d_loc = t>>2, qtr = t&3;
      int d = pass*64 + d_loc;
      int tok0 = R + qtr*32;
      long base;
      if (is_img) base = ((long)hd*128 + d)*2048 + tok0;
      else { int b_ = tok0>>9, s_ = tok0&511; base = ((long)(b_*24+hd)*128 + d)*512 + s_; }
      #pragma unroll
      for (int k2=0;k2<4;k2++)
        *(u16x8*)(Vd + base + k2*8) = *(const u16x8*)&SHT[d_loc*136 + qtr*32 + k2*8];
    }
    return;
  }

  // ---- fused RMSNorm + RoPE epilogue (Q/K) ----
  float part[4][4];
  #pragma unroll
  for (int m=0;m<4;m++)
    #pragma unroll
    for (int r=0;r<4;r++){
      float s_ = 0.f;
      #pragma unroll
      for (int n=0;n<4;n++){ float v = acc[m][n][r] + bias_n[n]; s_ += v*v; }
      part[m][r] = s_;
    }
  #pragma unroll
  for (int m=0;m<4;m++)
    #pragma unroll
    for (int r=0;r<4;r++){
      part[m][r] += __shfl_xor(part[m][r], 1);
      part[m][r] += __shfl_xor(part[m][r], 2);
      part[m][r] += __shfl_xor(part[m][r], 4);
      part[m][r] += __shfl_xor(part[m][r], 8);
    }
  __syncthreads();                                   // staging reads done; reuse SH
  float* rs = (float*)SH;                            // [2 wc][2 wr][64 row]
  if (li == 0){
    #pragma unroll
    for (int m=0;m<4;m++)
      #pragma unroll
      for (int r=0;r<4;r++)
        rs[(wc*2+wr)*64 + m*16 + g*4 + r] = part[m][r];
  }
  __syncthreads();
  float fac[4][4];
  #pragma unroll
  for (int m=0;m<4;m++)
    #pragma unroll
    for (int r=0;r<4;r++){
      int idx = m*16 + g*4 + r;
      float tot = rs[(0*2+wr)*64 + idx] + rs[(1*2+wr)*64 + idx];
      fac[m][r] = rsqrtf(tot*(1.0f/128.0f) + 1e-6f);
    }

  const float* nw = (sec==0) ? nqw : nkw;
  const float qs = (sec==0) ? (float)(0.08838834764831845 * 1.4426950408889634) : 1.0f;
  float nw_n[4];
  #pragma unroll
  for (int n=0;n<4;n++) nw_n[n] = nw[wc*64 + n*16 + li];

  #pragma unroll
  for (int m=0;m<4;m++){
    #pragma unroll
    for (int r=0;r<4;r++){
      int row_l = wr*64 + m*16 + g*4 + r;
      int t_row = R + row_l;
      int b_, s_, p_;
      if (is_img){ b_ = t_row>>10; s_ = t_row&1023; p_ = 512+s_; }
      else       { b_ = t_row>>9;  s_ = t_row&511;  p_ = s_; }
      long didx;
      if (sec==0) didx = (long)(b_*24+hd)*1536 + (is_img ? 512+s_ : s_);
      else        didx = is_img ? ((long)hd*2048 + t_row) : ((long)(b_*24+hd)*512 + s_);
      const float* crow = cs + (long)p_*128;
      const float* srow = sn + (long)p_*128;
      unsigned short* drow = ((sec==0)?Qd:Kd) + didx*128;
      #pragma unroll
      for (int n=0;n<4;n++){
        int cl = wc*64 + n*16 + li;
        float x = (acc[m][n][r] + bias_n[n]) * fac[m][r] * nw_n[n];
        float xo = __shfl_xor(x, 1);
        float o_ = x*crow[cl] + ((l&1) ? xo*srow[cl] : -xo*srow[cl]);
        drow[cl] = f2bf(o_*qs);
      }
    }
  }
}

// ---------------- fused output GEMM (block-diagonal over rows) ----------------
__global__ __launch_bounds__(256) void k_gemmO(
    const unsigned short* __restrict__ X, const unsigned short* __restrict__ Wf,
    float* __restrict__ out, const float* __restrict__ bo, const float* __restrict__ bao)
{
  const int K = 3072;
  __shared__ unsigned short As[2][4096];
  __shared__ unsigned short Bs[2][4096];
  const int t = threadIdx.x, w = t>>6, l = t&63;
  const int bx = blockIdx.x, by = blockIdx.y;
  const bool enc = bx >= 16;
  const unsigned short* Wp = Wf + (enc ? 9437184 : 0);
  const float* bias = enc ? bao : bo;
  const int R = bx*128, C = by*128;
  long xbase, obase;
  if (!enc){ xbase = (long)(R>>10)*1536 + 512 + (R&1023); obase = (long)R*3072; }
  else { int Rp = R-2048; xbase = (long)(Rp>>9)*1536 + (Rp&511); obase = 6291456 + (long)Rp*3072; }
  const int wr = w>>1, wc = w&1;
  f32x4 acc[4][4] = {};

  auto stage = [&](int buf, int kt){
    const int k0 = kt*32;
    #pragma unroll
    for (int c=0;c<2;c++){
      int row = c*64 + (t>>2);
      int scol = ((t&3)<<3) ^ ((row&3)<<3) ^ (((row>>3)&1)<<4);
      gll16(X + (xbase+row)*K + k0 + scol, &As[buf][c*2048 + w*512]);
      gll16(Wp + (long)(C+row)*K + k0 + scol, &Bs[buf][c*2048 + w*512]);
    }
  };

  stage(0,0);
  int buf = 0;
  for (int kt=0; kt<96; kt++){
    __syncthreads();
    if (kt+1 < 96) stage(buf^1, kt+1);
    bf16x8 a[4], b[4];
    #pragma unroll
    for (int m=0;m<4;m++){
      int ar = wr*64 + m*16 + (l&15);
      int ac = ((l>>4)<<3) ^ ((ar&3)<<3) ^ (((ar>>3)&1)<<4);
      a[m] = *(const bf16x8*)&As[buf][ar*32 + ac];
      int br = wc*64 + m*16 + (l&15);
      int bc2 = ((l>>4)<<3) ^ ((br&3)<<3) ^ (((br>>3)&1)<<4);
      b[m] = *(const bf16x8*)&Bs[buf][br*32 + bc2];
    }
    #pragma unroll
    for (int m=0;m<4;m++)
      #pragma unroll
      for (int n=0;n<4;n++)
        acc[m][n] = __builtin_amdgcn_mfma_f32_16x16x32_bf16(a[m], b[n], acc[m][n], 0,0,0);
    buf ^= 1;
  }

  #pragma unroll
  for (int m=0;m<4;m++){
    int rl = wr*64 + m*16 + ((l>>4)<<2);
    #pragma unroll
    for (int n=0;n<4;n++){
      int col = C + wc*64 + n*16 + (l&15);
      float bvv = bias[col];
      #pragma unroll
      for (int r=0;r<4;r++)
        out[obase + (long)(rl+r)*3072 + col] = acc[m][n][r] + bvv;
    }
  }
}

// ---------------- flash attention (round-6/8 proven schedule) ----------------
__global__ __launch_bounds__(256) void k_attn(
    const unsigned short* __restrict__ Q,
    const unsigned short* __restrict__ Ke, const unsigned short* __restrict__ Ki,
    const unsigned short* __restrict__ Ve, const unsigned short* __restrict__ Vi,
    unsigned short* __restrict__ AO)
{
  __shared__ unsigned short Ks[8192];          // [64 kv][128 d], XOR-swizzled
  __shared__ unsigned short Vs[8192];          // [128 d][64 kv], XOR-swizzled
  __shared__ unsigned short Ps[4][1408];       // per-wave P tile [16 q][88 k-pad]
  const int t = threadIdx.x, w = t>>6, l = t&63;
  const int h = blockIdx.y, b = blockIdx.z;
  const int bh = b*24 + h;
  const int q0 = blockIdx.x*64 + w*16;
  const int g = l>>4;

  auto stageK = [&](int jt){
    const unsigned short* ksrc = (jt < 8) ? Ke + ((long)bh*512 + jt*64)*128
                                          : Ki + ((long)h*2048 + (jt-8)*64)*128;
    #pragma unroll
    for (int c=0;c<4;c++){
      int row = c*16 + (t>>4);
      int col = ((t&15)<<3) ^ ((row&7)<<3);
      gll16(ksrc + row*128 + col, &Ks[c*2048 + w*512]);
    }
  };
  auto stageV = [&](int jt){
    const unsigned short* vsrc; long vstr;
    if (jt < 8){ vsrc = Ve + (long)bh*65536 + jt*64; vstr = 512; }
    else { vsrc = Vi + (long)h*262144 + (jt-8)*64; vstr = 2048; }
    #pragma unroll
    for (int c=0;c<4;c++){
      int row = c*32 + (t>>3);
      int col = ((t&7)<<3) ^ ((row&7)<<3);
      gll16(vsrc + (long)row*vstr + col, &Vs[c*2048 + w*512]);
    }
  };

  bf16x8 qf[4];
  {
    const unsigned short* qp = Q + ((long)bh*1536 + q0 + (l&15))*128 + (g<<3);
    #pragma unroll
    for (int kc=0;kc<4;kc++) qf[kc] = *(const bf16x8*)(qp + kc*32);
  }
  f32x4 o[8] = {};
  float mx = -1e30f;
  float ls = 0.f;            // per-lane partial sum over own (q, k-slice)

  stageK(0);
  for (int jt=0; jt<40; jt++){
    __syncthreads();                 // K(jt) landed; all waves past PV(jt-1)
    stageV(jt);                      // covered by QK + softmax below

    // S^T tile: sf[ct][r] = S[q = q0 + (l&15)][k = ct*16 + g*4 + r]
    f32x4 sf[4];
    __builtin_amdgcn_s_setprio(1);
    #pragma unroll
    for (int ct=0;ct<4;ct++){
      f32x4 s = {};
      #pragma unroll
      for (int kc=0;kc<4;kc++){
        int krow = ct*16 + (l&15);
        int kcol = (kc*32 + (g<<3)) ^ ((krow&7)<<3);
        bf16x8 kb = *(const bf16x8*)&Ks[krow*128 + kcol];
        s = __builtin_amdgcn_mfma_f32_16x16x32_bf16(kb, qf[kc], s, 0,0,0);  // SWAPPED
      }
      sf[ct] = s;
    }
    __builtin_amdgcn_s_setprio(0);

    // per-lane slice max (own q); defer-max with THR=8 (log2 domain)
    float pm = sf[0][0];
    #pragma unroll
    for (int ct=0;ct<4;ct++)
      #pragma unroll
      for (int r=0;r<4;r++) pm = fmaxf(pm, sf[ct][r]);
    if (!__all(pm <= mx + 8.0f)){
      float tmax = pm;
      tmax = fmaxf(tmax, __shfl_xor(tmax, 16));
      tmax = fmaxf(tmax, __shfl_xor(tmax, 32));     // full-row max for own q
      float mn = fmaxf(mx, tmax);
      float al = exp2f(mx - mn);
      mx = mn;
      ls *= al;
      #pragma unroll
      for (int r=0;r<4;r++){
        float alo = __shfl(al, (l&48) | ((g<<2)+r));  // factor for o-row q' = 4g+r
        #pragma unroll
        for (int f=0;f<8;f++) o[f][r] *= alo;
      }
    }
    // P = exp2(S - mx), pack pairs, write b64; accumulate per-lane ls
    #pragma unroll
    for (int ct=0;ct<4;ct++){
      float p0 = exp2f(sf[ct][0]-mx), p1 = exp2f(sf[ct][1]-mx);
      float p2 = exp2f(sf[ct][2]-mx), p3 = exp2f(sf[ct][3]-mx);
      ls += (p0+p1)+(p2+p3);
      uint2v pk = { cvtpk(p0,p1), cvtpk(p2,p3) };
      *(uint2v*)&Ps[w][(l&15)*88 + ct*16 + (g<<2)] = pk;
    }
    __syncthreads();                 // V(jt) landed; all waves done reading Ks

    if (jt+1 < 40) stageK(jt+1);     // overwrites Ks; covered by PV below

    bf16x8 pa[2];
    #pragma unroll
    for (int kc=0;kc<2;kc++)
      pa[kc] = *(const bf16x8*)&Ps[w][(l&15)*88 + kc*32 + (g<<3)];
    __builtin_amdgcn_s_setprio(1);
    #pragma unroll
    for (int f=0;f<8;f++){
      #pragma unroll
      for (int kc=0;kc<2;kc++){
        int vrow = f*16 + (l&15);
        int vcol = (kc*32 + (g<<3)) ^ ((vrow&7)<<3);
        bf16x8 vb = *(const bf16x8*)&Vs[vrow*64 + vcol];
        o[f] = __builtin_amdgcn_mfma_f32_16x16x32_bf16(pa[kc], vb, o[f], 0,0,0);
      }
    }
    __builtin_amdgcn_s_setprio(0);
  }

  // finalize: full row-sum for own q, then fetch for o-rows q' = 4g+r
  ls += __shfl_xor(ls, 16);
  ls += __shfl_xor(ls, 32);
  #pragma unroll
  for (int r=0;r<4;r++){
    float lso = __shfl(ls, (l&48) | ((g<<2)+r));
    float inv = 1.0f/lso;
    int qrow = q0 + (g<<2) + r;
    #pragma unroll
    for (int f=0;f<8;f++){
      AO[((long)b*1536 + qrow)*3072 + h*128 + f*16 + (l&15)] = f2bf(o[f][r]*inv);
    }
  }
}

// ---------------- host launch ----------------
extern "C" void kernel_launch(void* const* d_in, const int* in_sizes, int n_in,
                              void* d_out, int out_size, void* d_ws, size_t ws_size,
                              hipStream_t stream)
{
  const float* hs  = (const float*)d_in[0];
  const float* ehs = (const float*)d_in[1];
  const float* rc  = (const float*)d_in[2];
  const float* rs_ = (const float*)d_in[3];
  const float* wq = (const float*)d_in[4];  const float* bq = (const float*)d_in[5];
  const float* wk = (const float*)d_in[6];  const float* bk = (const float*)d_in[7];
  const float* wv = (const float*)d_in[8];  const float* bv = (const float*)d_in[9];
  const float* waq= (const float*)d_in[10]; const float* baq= (const float*)d_in[11];
  const float* wak= (const float*)d_in[12]; const float* bak= (const float*)d_in[13];
  const float* wav= (const float*)d_in[14]; const float* bav= (const float*)d_in[15];
  const float* wo = (const float*)d_in[16]; const float* bo = (const float*)d_in[17];
  const float* wao= (const float*)d_in[18]; const float* bao= (const float*)d_in[19];
  const float* nq = (const float*)d_in[20]; const float* nk = (const float*)d_in[21];
  const float* naq= (const float*)d_in[22]; const float* nak= (const float*)d_in[23];

  char* p = (char*)d_ws;
  auto alloc = [&](size_t bytes){ char* r = p; p += bytes; return r; };

  if (ws_size >= (size_t)188743680){
    // ---------- main path (188.7 MB) ----------
    unsigned short* Xh = (unsigned short*)alloc(12582912);  // [2048][3072]
    unsigned short* Xe = (unsigned short*)alloc(6291456);   // [1024][3072]
    unsigned short* Wb = (unsigned short*)alloc(113246208); // 6 weight slots bf16
    unsigned short* Qb = (unsigned short*)alloc(18874368);  // Q [2][24][1536][128]
    unsigned short* Ke = (unsigned short*)alloc(6291456);   // Kenc [2][24][512][128]
    unsigned short* Ki = (unsigned short*)alloc(12582912);  // Kimg [24][2048][128]
    unsigned short* Ve = (unsigned short*)alloc(6291456);   // Vtenc [2][24][128][512]
    unsigned short* Vi = (unsigned short*)alloc(12582912);  // Vtimg [24][128][2048]
    unsigned short* AO = Xh;                                // aliases Xh+Xe (dead by attn)

    k_cast<<<6144,256,0,stream>>>(hs, Xh, 1572864);
    k_cast<<<3072,256,0,stream>>>(ehs, Xe, 786432);
    k_castW<<<55296,256,0,stream>>>(wq, wk, wv, waq, wak, wav, Wb);

    k_gemmP<<<dim3(16,72),256,0,stream>>>(Xh, Wb, bq, bk, bv,
                                          nq, nk, rc, rs_, Qb, Ki, Vi, 1);
    k_gemmP<<<dim3(8,72),256,0,stream>>>(Xe, Wb + 28311552, baq, bak, bav,
                                         naq, nak, rc, rs_, Qb, Ke, Ve, 0);

    k_attn<<<dim3(24,24,2),256,0,stream>>>(Qb, Ke, Ki, Ve, Vi, AO);

    k_castW2<<<18432,256,0,stream>>>(wo, wao, Wb);
    k_gemmO<<<dim3(24,24),256,0,stream>>>(AO, Wb, (float*)d_out, bo, bao);
  } else {
    // ---------- fallback path (132.1 MB): 3 weight slots, groups sequential ----------
    unsigned short* Xh = (unsigned short*)alloc(12582912);
    unsigned short* Xe = (unsigned short*)alloc(6291456);
    unsigned short* Wb = (unsigned short*)alloc(56623104);  // 3 slots
    unsigned short* Qb = (unsigned short*)alloc(18874368);
    unsigned short* Ke = (unsigned short*)alloc(6291456);
    unsigned short* Ki = (unsigned short*)alloc(12582912);
    unsigned short* Ve = (unsigned short*)alloc(6291456);
    unsigned short* Vi = (unsigned short*)alloc(12582912);
    unsigned short* AO = Xh;

    k_cast<<<6144,256,0,stream>>>(hs, Xh, 1572864);
    k_cast<<<3072,256,0,stream>>>(ehs, Xe, 786432);

    k_cast<<<9216,256,0,stream>>>(wq, Wb, 2359296);
    k_cast<<<9216,256,0,stream>>>(wk, Wb + 9437184, 2359296);
    k_cast<<<9216,256,0,stream>>>(wv, Wb + 18874368, 2359296);
    k_gemmP<<<dim3(16,72),256,0,stream>>>(Xh, Wb, bq, bk, bv,
                                          nq, nk, rc, rs_, Qb, Ki, Vi, 1);

    k_cast<<<9216,256,0,stream>>>(waq, Wb, 2359296);
    k_cast<<<9216,256,0,stream>>>(wak, Wb + 9437184, 2359296);
    k_cast<<<9216,256,0,stream>>>(wav, Wb + 18874368, 2359296);
    k_gemmP<<<dim3(8,72),256,0,stream>>>(Xe, Wb, baq, bak, bav,
                                         naq, nak, rc, rs_, Qb, Ke, Ve, 0);

    k_attn<<<dim3(24,24,2),256,0,stream>>>(Qb, Ke, Ki, Ve, Vi, AO);

    k_castW2<<<18432,256,0,stream>>>(wo, wao, Wb);
    k_gemmO<<<dim3(24,24),256,0,stream>>>(AO, Wb, (float*)d_out, bo, bao);
  }
}

// Round 10
// 692.913 us; speedup vs baseline: 1.0303x; 1.0303x over previous
//
#include <hip/hip_runtime.h>

typedef __attribute__((ext_vector_type(8))) short bf16x8;
typedef __attribute__((ext_vector_type(8))) unsigned short u16x8;
typedef __attribute__((ext_vector_type(4))) unsigned short u16x4;
typedef __attribute__((ext_vector_type(4))) float f32x4;
typedef __attribute__((ext_vector_type(2))) unsigned uint2v;

#define DEV static __device__ __forceinline__

DEV unsigned short f2bf(float f){
  unsigned u = __float_as_uint(f);
  u += 0x7fff + ((u>>16)&1);
  return (unsigned short)(u>>16);
}
DEV float bf2f(unsigned short b){ return __uint_as_float(((unsigned)b)<<16); }
DEV unsigned cvtpk(float lo, float hi){
  unsigned r;
  asm("v_cvt_pk_bf16_f32 %0, %1, %2" : "=v"(r) : "v"(lo), "v"(hi));
  return r;
}

DEV void gll16(const void* g, void* l){
  __builtin_amdgcn_global_load_lds((__attribute__((address_space(1))) unsigned*)(void*)g,
                                   (__attribute__((address_space(3))) unsigned*)l, 16, 0, 0);
}

// ---------------- cast fp32 -> bf16 (vectorized) ----------------
__global__ void k_cast(const float* __restrict__ x, unsigned short* __restrict__ y, int n4){
  int i = blockIdx.x*256 + threadIdx.x;
  if (i >= n4) return;
  f32x4 v = ((const f32x4*)x)[i];
  u16x4 o = { f2bf(v.x), f2bf(v.y), f2bf(v.z), f2bf(v.w) };
  ((u16x4*)y)[i] = o;
}

// ---------------- 6-segment weight cast ----------------
__global__ void k_castW(const float* __restrict__ s0, const float* __restrict__ s1,
                        const float* __restrict__ s2, const float* __restrict__ s3,
                        const float* __restrict__ s4, const float* __restrict__ s5,
                        unsigned short* __restrict__ y){
  unsigned i = blockIdx.x*256 + threadIdx.x;          // < 6*2359296
  unsigned seg = i / 2359296u;
  unsigned off = i - seg*2359296u;
  const float* s = seg==0?s0: seg==1?s1: seg==2?s2: seg==3?s3: seg==4?s4: s5;
  f32x4 v = ((const f32x4*)s)[off];
  u16x4 o = { f2bf(v.x), f2bf(v.y), f2bf(v.z), f2bf(v.w) };
  ((u16x4*)y)[i] = o;
}

// ---------------- 2-segment weight cast (wo/wao) ----------------
__global__ void k_castW2(const float* __restrict__ s0, const float* __restrict__ s1,
                         unsigned short* __restrict__ y){
  unsigned i = blockIdx.x*256 + threadIdx.x;          // < 2*2359296
  unsigned seg = i / 2359296u;
  unsigned off = i - seg*2359296u;
  const float* s = seg==0?s0:s1;
  f32x4 v = ((const f32x4*)s)[off];
  u16x4 o = { f2bf(v.x), f2bf(v.y), f2bf(v.z), f2bf(v.w) };
  ((u16x4*)y)[i] = o;
}

// ---------------- QKV projection GEMM, fully fused epilogues ----------------
// sec0 (Q): RMS(nq)+RoPE(qsc) -> Qd ; sec1 (K): RMS(nk)+RoPE -> Kd ;
// sec2 (V): 2-pass LDS-transpose -> Vd[(b,)h][d][tok] (SH = 32 KB exactly).
// NOTE: plain __launch_bounds__(256) — the (256,5) hint forced VGPR=48 and
// spilled the 64-VGPR accumulator to scratch (round 9: WRITE_SIZE 37->102 MB).
__global__ __launch_bounds__(256) void k_gemmP(
    const unsigned short* __restrict__ X, const unsigned short* __restrict__ W,
    const float* __restrict__ b0, const float* __restrict__ b1, const float* __restrict__ b2,
    const float* __restrict__ nqw, const float* __restrict__ nkw,
    const float* __restrict__ cs, const float* __restrict__ sn,
    unsigned short* __restrict__ Qd, unsigned short* __restrict__ Kd,
    unsigned short* __restrict__ Vd,
    int is_img)
{
  const int K = 3072;
  __shared__ unsigned short SH[16384];                // exactly 32768 B
  unsigned short (*As)[4096] = (unsigned short(*)[4096])SH;
  unsigned short (*Bs)[4096] = (unsigned short(*)[4096])(SH + 8192);
  const int t = threadIdx.x, w = t>>6, l = t&63;
  const int li = l&15, g = l>>4;
  const int by = blockIdx.y, bx = blockIdx.x;
  const int sec = by>=48 ? 2 : (by>=24 ? 1 : 0);
  const int hd = by - sec*24;
  const int Cl = hd*128;
  const int R = bx*128;
  const unsigned short* Wp = W + (long)sec*9437184 + (long)Cl*K;
  const float* bias = (sec==0)?b0:(sec==1)?b1:b2;
  const int wr = w>>1, wc = w&1;
  f32x4 acc[4][4] = {};

  auto stage = [&](int buf, int kt){
    const int k0 = kt*32;
    #pragma unroll
    for (int c=0;c<2;c++){
      int row = c*64 + (t>>2);
      int scol = ((t&3)<<3) ^ ((row&3)<<3) ^ (((row>>3)&1)<<4);
      gll16(X + (long)(R+row)*K + k0 + scol, &As[buf][c*2048 + w*512]);
      gll16(Wp + (long)row*K + k0 + scol, &Bs[buf][c*2048 + w*512]);
    }
  };

  stage(0,0);
  int buf = 0;
  for (int kt=0; kt<96; kt++){
    __syncthreads();
    if (kt+1 < 96) stage(buf^1, kt+1);
    bf16x8 a[4], b[4];
    #pragma unroll
    for (int m=0;m<4;m++){
      int ar = wr*64 + m*16 + li;
      int ac = (g<<3) ^ ((ar&3)<<3) ^ (((ar>>3)&1)<<4);
      a[m] = *(const bf16x8*)&As[buf][ar*32 + ac];
      int br = wc*64 + m*16 + li;
      int bc2 = (g<<3) ^ ((br&3)<<3) ^ (((br>>3)&1)<<4);
      b[m] = *(const bf16x8*)&Bs[buf][br*32 + bc2];
    }
    #pragma unroll
    for (int m=0;m<4;m++)
      #pragma unroll
      for (int n=0;n<4;n++)
        acc[m][n] = __builtin_amdgcn_mfma_f32_16x16x32_bf16(a[m], b[n], acc[m][n], 0,0,0);
    buf ^= 1;
  }

  float bias_n[4];
  #pragma unroll
  for (int n=0;n<4;n++) bias_n[n] = bias[Cl + wc*64 + n*16 + li];

  if (sec == 2){
    // ---- V: 2-pass LDS-transpose epilogue (SHT[64 d][136 tok]) ----
    unsigned short* SHT = SH;
    #pragma unroll
    for (int pass=0; pass<2; pass++){
      __syncthreads();                               // staging / prev-pass reads done
      if (wc == pass){
        #pragma unroll
        for (int m=0;m<4;m++){
          int tok_l = wr*64 + m*16 + (g<<2);
          #pragma unroll
          for (int n=0;n<4;n++){
            int col_loc = n*16 + li;                 // 0..63 within this pass
            u16x4 v4 = { f2bf(acc[m][n][0]+bias_n[n]), f2bf(acc[m][n][1]+bias_n[n]),
                         f2bf(acc[m][n][2]+bias_n[n]), f2bf(acc[m][n][3]+bias_n[n]) };
            *(u16x4*)&SHT[col_loc*136 + tok_l] = v4;
          }
        }
      }
      __syncthreads();
      int d_loc = t>>2, qtr = t&3;
      int d = pass*64 + d_loc;
      int tok0 = R + qtr*32;
      long base;
      if (is_img) base = ((long)hd*128 + d)*2048 + tok0;
      else { int b_ = tok0>>9, s_ = tok0&511; base = ((long)(b_*24+hd)*128 + d)*512 + s_; }
      #pragma unroll
      for (int k2=0;k2<4;k2++)
        *(u16x8*)(Vd + base + k2*8) = *(const u16x8*)&SHT[d_loc*136 + qtr*32 + k2*8];
    }
    return;
  }

  // ---- fused RMSNorm + RoPE epilogue (Q/K) ----
  float part[4][4];
  #pragma unroll
  for (int m=0;m<4;m++)
    #pragma unroll
    for (int r=0;r<4;r++){
      float s_ = 0.f;
      #pragma unroll
      for (int n=0;n<4;n++){ float v = acc[m][n][r] + bias_n[n]; s_ += v*v; }
      part[m][r] = s_;
    }
  #pragma unroll
  for (int m=0;m<4;m++)
    #pragma unroll
    for (int r=0;r<4;r++){
      part[m][r] += __shfl_xor(part[m][r], 1);
      part[m][r] += __shfl_xor(part[m][r], 2);
      part[m][r] += __shfl_xor(part[m][r], 4);
      part[m][r] += __shfl_xor(part[m][r], 8);
    }
  __syncthreads();                                   // staging reads done; reuse SH
  float* rs = (float*)SH;                            // [2 wc][2 wr][64 row]
  if (li == 0){
    #pragma unroll
    for (int m=0;m<4;m++)
      #pragma unroll
      for (int r=0;r<4;r++)
        rs[(wc*2+wr)*64 + m*16 + g*4 + r] = part[m][r];
  }
  __syncthreads();
  float fac[4][4];
  #pragma unroll
  for (int m=0;m<4;m++)
    #pragma unroll
    for (int r=0;r<4;r++){
      int idx = m*16 + g*4 + r;
      float tot = rs[(0*2+wr)*64 + idx] + rs[(1*2+wr)*64 + idx];
      fac[m][r] = rsqrtf(tot*(1.0f/128.0f) + 1e-6f);
    }

  const float* nw = (sec==0) ? nqw : nkw;
  const float qs = (sec==0) ? (float)(0.08838834764831845 * 1.4426950408889634) : 1.0f;
  float nw_n[4];
  #pragma unroll
  for (int n=0;n<4;n++) nw_n[n] = nw[wc*64 + n*16 + li];

  #pragma unroll
  for (int m=0;m<4;m++){
    #pragma unroll
    for (int r=0;r<4;r++){
      int row_l = wr*64 + m*16 + g*4 + r;
      int t_row = R + row_l;
      int b_, s_, p_;
      if (is_img){ b_ = t_row>>10; s_ = t_row&1023; p_ = 512+s_; }
      else       { b_ = t_row>>9;  s_ = t_row&511;  p_ = s_; }
      long didx;
      if (sec==0) didx = (long)(b_*24+hd)*1536 + (is_img ? 512+s_ : s_);
      else        didx = is_img ? ((long)hd*2048 + t_row) : ((long)(b_*24+hd)*512 + s_);
      const float* crow = cs + (long)p_*128;
      const float* srow = sn + (long)p_*128;
      unsigned short* drow = ((sec==0)?Qd:Kd) + didx*128;
      #pragma unroll
      for (int n=0;n<4;n++){
        int cl = wc*64 + n*16 + li;
        float x = (acc[m][n][r] + bias_n[n]) * fac[m][r] * nw_n[n];
        float xo = __shfl_xor(x, 1);
        float o_ = x*crow[cl] + ((l&1) ? xo*srow[cl] : -xo*srow[cl]);
        drow[cl] = f2bf(o_*qs);
      }
    }
  }
}

// ---------------- fused output GEMM (block-diagonal over rows) ----------------
__global__ __launch_bounds__(256) void k_gemmO(
    const unsigned short* __restrict__ X, const unsigned short* __restrict__ Wf,
    float* __restrict__ out, const float* __restrict__ bo, const float* __restrict__ bao)
{
  const int K = 3072;
  __shared__ unsigned short As[2][4096];
  __shared__ unsigned short Bs[2][4096];
  const int t = threadIdx.x, w = t>>6, l = t&63;
  const int bx = blockIdx.x, by = blockIdx.y;
  const bool enc = bx >= 16;
  const unsigned short* Wp = Wf + (enc ? 9437184 : 0);
  const float* bias = enc ? bao : bo;
  const int R = bx*128, C = by*128;
  long xbase, obase;
  if (!enc){ xbase = (long)(R>>10)*1536 + 512 + (R&1023); obase = (long)R*3072; }
  else { int Rp = R-2048; xbase = (long)(Rp>>9)*1536 + (Rp&511); obase = 6291456 + (long)Rp*3072; }
  const int wr = w>>1, wc = w&1;
  f32x4 acc[4][4] = {};

  auto stage = [&](int buf, int kt){
    const int k0 = kt*32;
    #pragma unroll
    for (int c=0;c<2;c++){
      int row = c*64 + (t>>2);
      int scol = ((t&3)<<3) ^ ((row&3)<<3) ^ (((row>>3)&1)<<4);
      gll16(X + (xbase+row)*K + k0 + scol, &As[buf][c*2048 + w*512]);
      gll16(Wp + (long)(C+row)*K + k0 + scol, &Bs[buf][c*2048 + w*512]);
    }
  };

  stage(0,0);
  int buf = 0;
  for (int kt=0; kt<96; kt++){
    __syncthreads();
    if (kt+1 < 96) stage(buf^1, kt+1);
    bf16x8 a[4], b[4];
    #pragma unroll
    for (int m=0;m<4;m++){
      int ar = wr*64 + m*16 + (l&15);
      int ac = ((l>>4)<<3) ^ ((ar&3)<<3) ^ (((ar>>3)&1)<<4);
      a[m] = *(const bf16x8*)&As[buf][ar*32 + ac];
      int br = wc*64 + m*16 + (l&15);
      int bc2 = ((l>>4)<<3) ^ ((br&3)<<3) ^ (((br>>3)&1)<<4);
      b[m] = *(const bf16x8*)&Bs[buf][br*32 + bc2];
    }
    #pragma unroll
    for (int m=0;m<4;m++)
      #pragma unroll
      for (int n=0;n<4;n++)
        acc[m][n] = __builtin_amdgcn_mfma_f32_16x16x32_bf16(a[m], b[n], acc[m][n], 0,0,0);
    buf ^= 1;
  }

  #pragma unroll
  for (int m=0;m<4;m++){
    int rl = wr*64 + m*16 + ((l>>4)<<2);
    #pragma unroll
    for (int n=0;n<4;n++){
      int col = C + wc*64 + n*16 + (l&15);
      float bvv = bias[col];
      #pragma unroll
      for (int r=0;r<4;r++)
        out[obase + (long)(rl+r)*3072 + col] = acc[m][n][r] + bvv;
    }
  }
}

// ---------------- flash attention (round-6/8 proven schedule) ----------------
__global__ __launch_bounds__(256) void k_attn(
    const unsigned short* __restrict__ Q,
    const unsigned short* __restrict__ Ke, const unsigned short* __restrict__ Ki,
    const unsigned short* __restrict__ Ve, const unsigned short* __restrict__ Vi,
    unsigned short* __restrict__ AO)
{
  __shared__ unsigned short Ks[8192];          // [64 kv][128 d], XOR-swizzled
  __shared__ unsigned short Vs[8192];          // [128 d][64 kv], XOR-swizzled
  __shared__ unsigned short Ps[4][1408];       // per-wave P tile [16 q][88 k-pad]
  const int t = threadIdx.x, w = t>>6, l = t&63;
  const int h = blockIdx.y, b = blockIdx.z;
  const int bh = b*24 + h;
  const int q0 = blockIdx.x*64 + w*16;
  const int g = l>>4;

  auto stageK = [&](int jt){
    const unsigned short* ksrc = (jt < 8) ? Ke + ((long)bh*512 + jt*64)*128
                                          : Ki + ((long)h*2048 + (jt-8)*64)*128;
    #pragma unroll
    for (int c=0;c<4;c++){
      int row = c*16 + (t>>4);
      int col = ((t&15)<<3) ^ ((row&7)<<3);
      gll16(ksrc + row*128 + col, &Ks[c*2048 + w*512]);
    }
  };
  auto stageV = [&](int jt){
    const unsigned short* vsrc; long vstr;
    if (jt < 8){ vsrc = Ve + (long)bh*65536 + jt*64; vstr = 512; }
    else { vsrc = Vi + (long)h*262144 + (jt-8)*64; vstr = 2048; }
    #pragma unroll
    for (int c=0;c<4;c++){
      int row = c*32 + (t>>3);
      int col = ((t&7)<<3) ^ ((row&7)<<3);
      gll16(vsrc + (long)row*vstr + col, &Vs[c*2048 + w*512]);
    }
  };

  bf16x8 qf[4];
  {
    const unsigned short* qp = Q + ((long)bh*1536 + q0 + (l&15))*128 + (g<<3);
    #pragma unroll
    for (int kc=0;kc<4;kc++) qf[kc] = *(const bf16x8*)(qp + kc*32);
  }
  f32x4 o[8] = {};
  float mx = -1e30f;
  float ls = 0.f;            // per-lane partial sum over own (q, k-slice)

  stageK(0);
  for (int jt=0; jt<40; jt++){
    __syncthreads();                 // K(jt) landed; all waves past PV(jt-1)
    stageV(jt);                      // covered by QK + softmax below

    // S^T tile: sf[ct][r] = S[q = q0 + (l&15)][k = ct*16 + g*4 + r]
    f32x4 sf[4];
    __builtin_amdgcn_s_setprio(1);
    #pragma unroll
    for (int ct=0;ct<4;ct++){
      f32x4 s = {};
      #pragma unroll
      for (int kc=0;kc<4;kc++){
        int krow = ct*16 + (l&15);
        int kcol = (kc*32 + (g<<3)) ^ ((krow&7)<<3);
        bf16x8 kb = *(const bf16x8*)&Ks[krow*128 + kcol];
        s = __builtin_amdgcn_mfma_f32_16x16x32_bf16(kb, qf[kc], s, 0,0,0);  // SWAPPED
      }
      sf[ct] = s;
    }
    __builtin_amdgcn_s_setprio(0);

    // per-lane slice max (own q); defer-max with THR=8 (log2 domain)
    float pm = sf[0][0];
    #pragma unroll
    for (int ct=0;ct<4;ct++)
      #pragma unroll
      for (int r=0;r<4;r++) pm = fmaxf(pm, sf[ct][r]);
    if (!__all(pm <= mx + 8.0f)){
      float tmax = pm;
      tmax = fmaxf(tmax, __shfl_xor(tmax, 16));
      tmax = fmaxf(tmax, __shfl_xor(tmax, 32));     // full-row max for own q
      float mn = fmaxf(mx, tmax);
      float al = exp2f(mx - mn);
      mx = mn;
      ls *= al;
      #pragma unroll
      for (int r=0;r<4;r++){
        float alo = __shfl(al, (l&48) | ((g<<2)+r));  // factor for o-row q' = 4g+r
        #pragma unroll
        for (int f=0;f<8;f++) o[f][r] *= alo;
      }
    }
    // P = exp2(S - mx), pack pairs, write b64; accumulate per-lane ls
    #pragma unroll
    for (int ct=0;ct<4;ct++){
      float p0 = exp2f(sf[ct][0]-mx), p1 = exp2f(sf[ct][1]-mx);
      float p2 = exp2f(sf[ct][2]-mx), p3 = exp2f(sf[ct][3]-mx);
      ls += (p0+p1)+(p2+p3);
      uint2v pk = { cvtpk(p0,p1), cvtpk(p2,p3) };
      *(uint2v*)&Ps[w][(l&15)*88 + ct*16 + (g<<2)] = pk;
    }
    __syncthreads();                 // V(jt) landed; all waves done reading Ks

    if (jt+1 < 40) stageK(jt+1);     // overwrites Ks; covered by PV below

    bf16x8 pa[2];
    #pragma unroll
    for (int kc=0;kc<2;kc++)
      pa[kc] = *(const bf16x8*)&Ps[w][(l&15)*88 + kc*32 + (g<<3)];
    __builtin_amdgcn_s_setprio(1);
    #pragma unroll
    for (int f=0;f<8;f++){
      #pragma unroll
      for (int kc=0;kc<2;kc++){
        int vrow = f*16 + (l&15);
        int vcol = (kc*32 + (g<<3)) ^ ((vrow&7)<<3);
        bf16x8 vb = *(const bf16x8*)&Vs[vrow*64 + vcol];
        o[f] = __builtin_amdgcn_mfma_f32_16x16x32_bf16(pa[kc], vb, o[f], 0,0,0);
      }
    }
    __builtin_amdgcn_s_setprio(0);
  }

  // finalize: full row-sum for own q, then fetch for o-rows q' = 4g+r
  ls += __shfl_xor(ls, 16);
  ls += __shfl_xor(ls, 32);
  #pragma unroll
  for (int r=0;r<4;r++){
    float lso = __shfl(ls, (l&48) | ((g<<2)+r));
    float inv = 1.0f/lso;
    int qrow = q0 + (g<<2) + r;
    #pragma unroll
    for (int f=0;f<8;f++){
      AO[((long)b*1536 + qrow)*3072 + h*128 + f*16 + (l&15)] = f2bf(o[f][r]*inv);
    }
  }
}

// ---------------- host launch ----------------
extern "C" void kernel_launch(void* const* d_in, const int* in_sizes, int n_in,
                              void* d_out, int out_size, void* d_ws, size_t ws_size,
                              hipStream_t stream)
{
  const float* hs  = (const float*)d_in[0];
  const float* ehs = (const float*)d_in[1];
  const float* rc  = (const float*)d_in[2];
  const float* rs_ = (const float*)d_in[3];
  const float* wq = (const float*)d_in[4];  const float* bq = (const float*)d_in[5];
  const float* wk = (const float*)d_in[6];  const float* bk = (const float*)d_in[7];
  const float* wv = (const float*)d_in[8];  const float* bv = (const float*)d_in[9];
  const float* waq= (const float*)d_in[10]; const float* baq= (const float*)d_in[11];
  const float* wak= (const float*)d_in[12]; const float* bak= (const float*)d_in[13];
  const float* wav= (const float*)d_in[14]; const float* bav= (const float*)d_in[15];
  const float* wo = (const float*)d_in[16]; const float* bo = (const float*)d_in[17];
  const float* wao= (const float*)d_in[18]; const float* bao= (const float*)d_in[19];
  const float* nq = (const float*)d_in[20]; const float* nk = (const float*)d_in[21];
  const float* naq= (const float*)d_in[22]; const float* nak= (const float*)d_in[23];

  char* p = (char*)d_ws;
  auto alloc = [&](size_t bytes){ char* r = p; p += bytes; return r; };

  if (ws_size >= (size_t)188743680){
    // ---------- main path (188.7 MB) ----------
    unsigned short* Xh = (unsigned short*)alloc(12582912);  // [2048][3072]
    unsigned short* Xe = (unsigned short*)alloc(6291456);   // [1024][3072]
    unsigned short* Wb = (unsigned short*)alloc(113246208); // 6 weight slots bf16
    unsigned short* Qb = (unsigned short*)alloc(18874368);  // Q [2][24][1536][128]
    unsigned short* Ke = (unsigned short*)alloc(6291456);   // Kenc [2][24][512][128]
    unsigned short* Ki = (unsigned short*)alloc(12582912);  // Kimg [24][2048][128]
    unsigned short* Ve = (unsigned short*)alloc(6291456);   // Vtenc [2][24][128][512]
    unsigned short* Vi = (unsigned short*)alloc(12582912);  // Vtimg [24][128][2048]
    unsigned short* AO = Xh;                                // aliases Xh+Xe (dead by attn)

    k_cast<<<6144,256,0,stream>>>(hs, Xh, 1572864);
    k_cast<<<3072,256,0,stream>>>(ehs, Xe, 786432);
    k_castW<<<55296,256,0,stream>>>(wq, wk, wv, waq, wak, wav, Wb);

    k_gemmP<<<dim3(16,72),256,0,stream>>>(Xh, Wb, bq, bk, bv,
                                          nq, nk, rc, rs_, Qb, Ki, Vi, 1);
    k_gemmP<<<dim3(8,72),256,0,stream>>>(Xe, Wb + 28311552, baq, bak, bav,
                                         naq, nak, rc, rs_, Qb, Ke, Ve, 0);

    k_attn<<<dim3(24,24,2),256,0,stream>>>(Qb, Ke, Ki, Ve, Vi, AO);

    k_castW2<<<18432,256,0,stream>>>(wo, wao, Wb);
    k_gemmO<<<dim3(24,24),256,0,stream>>>(AO, Wb, (float*)d_out, bo, bao);
  } else {
    // ---------- fallback path (132.1 MB): 3 weight slots, groups sequential ----------
    unsigned short* Xh = (unsigned short*)alloc(12582912);
    unsigned short* Xe = (unsigned short*)alloc(6291456);
    unsigned short* Wb = (unsigned short*)alloc(56623104);  // 3 slots
    unsigned short* Qb = (unsigned short*)alloc(18874368);
    unsigned short* Ke = (unsigned short*)alloc(6291456);
    unsigned short* Ki = (unsigned short*)alloc(12582912);
    unsigned short* Ve = (unsigned short*)alloc(6291456);
    unsigned short* Vi = (unsigned short*)alloc(12582912);
    unsigned short* AO = Xh;

    k_cast<<<6144,256,0,stream>>>(hs, Xh, 1572864);
    k_cast<<<3072,256,0,stream>>>(ehs, Xe, 786432);

    k_cast<<<9216,256,0,stream>>>(wq, Wb, 2359296);
    k_cast<<<9216,256,0,stream>>>(wk, Wb + 9437184, 2359296);
    k_cast<<<9216,256,0,stream>>>(wv, Wb + 18874368, 2359296);
    k_gemmP<<<dim3(16,72),256,0,stream>>>(Xh, Wb, bq, bk, bv,
                                          nq, nk, rc, rs_, Qb, Ki, Vi, 1);

    k_cast<<<9216,256,0,stream>>>(waq, Wb, 2359296);
    k_cast<<<9216,256,0,stream>>>(wak, Wb + 9437184, 2359296);
    k_cast<<<9216,256,0,stream>>>(wav, Wb + 18874368, 2359296);
    k_gemmP<<<dim3(8,72),256,0,stream>>>(Xe, Wb, baq, bak, bav,
                                         naq, nak, rc, rs_, Qb, Ke, Ve, 0);

    k_attn<<<dim3(24,24,2),256,0,stream>>>(Qb, Ke, Ki, Ve, Vi, AO);

    k_castW2<<<18432,256,0,stream>>>(wo, wao, Wb);
    k_gemmO<<<dim3(24,24),256,0,stream>>>(AO, Wb, (float*)d_out, bo, bao);
  }
}

// Round 12
// 663.867 us; speedup vs baseline: 1.0753x; 1.0438x over previous
//
#include <hip/hip_runtime.h>

typedef __attribute__((ext_vector_type(8))) short bf16x8;
typedef __attribute__((ext_vector_type(8))) unsigned short u16x8;
typedef __attribute__((ext_vector_type(4))) unsigned short u16x4;
typedef __attribute__((ext_vector_type(4))) float f32x4;
typedef __attribute__((ext_vector_type(2))) unsigned uint2v;

#define DEV static __device__ __forceinline__

DEV unsigned short f2bf(float f){
  unsigned u = __float_as_uint(f);
  u += 0x7fff + ((u>>16)&1);
  return (unsigned short)(u>>16);
}
DEV float bf2f(unsigned short b){ return __uint_as_float(((unsigned)b)<<16); }
DEV unsigned cvtpk(float lo, float hi){
  unsigned r;
  asm("v_cvt_pk_bf16_f32 %0, %1, %2" : "=v"(r) : "v"(lo), "v"(hi));
  return r;
}

DEV void gll16(const void* g, void* l){
  __builtin_amdgcn_global_load_lds((__attribute__((address_space(1))) unsigned*)(void*)g,
                                   (__attribute__((address_space(3))) unsigned*)l, 16, 0, 0);
}

// ---------------- cast fp32 -> bf16 (vectorized) ----------------
__global__ void k_cast(const float* __restrict__ x, unsigned short* __restrict__ y, int n4){
  int i = blockIdx.x*256 + threadIdx.x;
  if (i >= n4) return;
  f32x4 v = ((const f32x4*)x)[i];
  u16x4 o = { f2bf(v.x), f2bf(v.y), f2bf(v.z), f2bf(v.w) };
  ((u16x4*)y)[i] = o;
}

// ---------------- 2-segment input cast (hs | ehs -> contiguous Xh,Xe) ----------------
__global__ void k_castX2(const float* __restrict__ s0, const float* __restrict__ s1,
                         unsigned short* __restrict__ y){
  unsigned i = blockIdx.x*256 + threadIdx.x;          // < 2359296
  const float* s = (i < 1572864u) ? s0 : s1;
  unsigned off = (i < 1572864u) ? i : i - 1572864u;
  f32x4 v = ((const f32x4*)s)[off];
  u16x4 o = { f2bf(v.x), f2bf(v.y), f2bf(v.z), f2bf(v.w) };
  ((u16x4*)y)[i] = o;
}

// ---------------- 8-segment weight cast (all weights, one launch) ----------------
__global__ void k_castW8(const float* __restrict__ s0, const float* __restrict__ s1,
                         const float* __restrict__ s2, const float* __restrict__ s3,
                         const float* __restrict__ s4, const float* __restrict__ s5,
                         const float* __restrict__ s6, const float* __restrict__ s7,
                         unsigned short* __restrict__ y){
  unsigned i = blockIdx.x*256 + threadIdx.x;          // < 8*2359296
  unsigned seg = i / 2359296u;                        // uniform per block
  unsigned off = i - seg*2359296u;
  const float* s = seg==0?s0: seg==1?s1: seg==2?s2: seg==3?s3:
                   seg==4?s4: seg==5?s5: seg==6?s6: s7;
  f32x4 v = ((const f32x4*)s)[off];
  u16x4 o = { f2bf(v.x), f2bf(v.y), f2bf(v.z), f2bf(v.w) };
  ((u16x4*)y)[i] = o;
}

// ---------------- 2-segment weight cast (fallback path) ----------------
__global__ void k_castW2(const float* __restrict__ s0, const float* __restrict__ s1,
                         unsigned short* __restrict__ y){
  unsigned i = blockIdx.x*256 + threadIdx.x;          // < 2*2359296
  unsigned seg = i / 2359296u;
  unsigned off = i - seg*2359296u;
  const float* s = seg==0?s0:s1;
  f32x4 v = ((const f32x4*)s)[off];
  u16x4 o = { f2bf(v.x), f2bf(v.y), f2bf(v.z), f2bf(v.w) };
  ((u16x4*)y)[i] = o;
}

// ---------------- merged QKV projection GEMM, fully fused epilogues ----------------
// Rows [0,rows_img): image tokens (Wimg, bq/bk/bv, nq/nk, Ki/Vi);
// rows >= rows_img: encoder tokens (Wenc, baq/bak/bav, naq/nak, Ke/Ve).
// sec0 (Q): RMS+RoPE -> Qd ; sec1 (K): RMS+RoPE -> Kdi/Kde ; sec2 (V): LDS-transpose -> Vdi/Vde.
__global__ __launch_bounds__(256) void k_gemmP(
    const unsigned short* __restrict__ X,
    const unsigned short* __restrict__ Wimg, const unsigned short* __restrict__ Wenc,
    const float* __restrict__ b0, const float* __restrict__ b1, const float* __restrict__ b2,
    const float* __restrict__ b3, const float* __restrict__ b4, const float* __restrict__ b5,
    const float* __restrict__ nq_, const float* __restrict__ nk_,
    const float* __restrict__ naq_, const float* __restrict__ nak_,
    const float* __restrict__ cs, const float* __restrict__ sn,
    unsigned short* __restrict__ Qd,
    unsigned short* __restrict__ Kdi, unsigned short* __restrict__ Kde,
    unsigned short* __restrict__ Vdi, unsigned short* __restrict__ Vde,
    int rows_img)
{
  const int K = 3072;
  __shared__ unsigned short SH[16384];                // exactly 32768 B
  unsigned short (*As)[4096] = (unsigned short(*)[4096])SH;
  unsigned short (*Bs)[4096] = (unsigned short(*)[4096])(SH + 8192);
  const int t = threadIdx.x, w = t>>6, l = t&63;
  const int li = l&15, g = l>>4;
  const int by = blockIdx.y, bx = blockIdx.x;
  const int sec = by>=48 ? 2 : (by>=24 ? 1 : 0);
  const int hd = by - sec*24;
  const int Cl = hd*128;
  const int R = bx*128;
  const bool img = (R < rows_img);                    // block-uniform
  const unsigned short* Wp = (img ? Wimg : Wenc) + (long)sec*9437184 + (long)Cl*K;
  const float* bias = img ? ((sec==0)?b0:(sec==1)?b1:b2)
                          : ((sec==0)?b3:(sec==1)?b4:b5);
  const int wr = w>>1, wc = w&1;
  f32x4 acc[4][4] = {};

  auto stage = [&](int buf, int kt){
    const int k0 = kt*32;
    #pragma unroll
    for (int c=0;c<2;c++){
      int row = c*64 + (t>>2);
      int scol = ((t&3)<<3) ^ ((row&3)<<3) ^ (((row>>3)&1)<<4);
      gll16(X + (long)(R+row)*K + k0 + scol, &As[buf][c*2048 + w*512]);
      gll16(Wp + (long)row*K + k0 + scol, &Bs[buf][c*2048 + w*512]);
    }
  };

  stage(0,0);
  int buf = 0;
  for (int kt=0; kt<96; kt++){
    __syncthreads();
    if (kt+1 < 96) stage(buf^1, kt+1);
    bf16x8 a[4], b[4];
    #pragma unroll
    for (int m=0;m<4;m++){
      int ar = wr*64 + m*16 + li;
      int ac = (g<<3) ^ ((ar&3)<<3) ^ (((ar>>3)&1)<<4);
      a[m] = *(const bf16x8*)&As[buf][ar*32 + ac];
      int br = wc*64 + m*16 + li;
      int bc2 = (g<<3) ^ ((br&3)<<3) ^ (((br>>3)&1)<<4);
      b[m] = *(const bf16x8*)&Bs[buf][br*32 + bc2];
    }
    #pragma unroll
    for (int m=0;m<4;m++)
      #pragma unroll
      for (int n=0;n<4;n++)
        acc[m][n] = __builtin_amdgcn_mfma_f32_16x16x32_bf16(a[m], b[n], acc[m][n], 0,0,0);
    buf ^= 1;
  }

  float bias_n[4];
  #pragma unroll
  for (int n=0;n<4;n++) bias_n[n] = bias[Cl + wc*64 + n*16 + li];

  if (sec == 2){
    // ---- V: 2-pass LDS-transpose epilogue (SHT[64 d][136 tok]) ----
    unsigned short* SHT = SH;
    unsigned short* Vd = img ? Vdi : Vde;
    #pragma unroll
    for (int pass=0; pass<2; pass++){
      __syncthreads();                               // staging / prev-pass reads done
      if (wc == pass){
        #pragma unroll
        for (int m=0;m<4;m++){
          int tok_l = wr*64 + m*16 + (g<<2);
          #pragma unroll
          for (int n=0;n<4;n++){
            int col_loc = n*16 + li;                 // 0..63 within this pass
            u16x4 v4 = { f2bf(acc[m][n][0]+bias_n[n]), f2bf(acc[m][n][1]+bias_n[n]),
                         f2bf(acc[m][n][2]+bias_n[n]), f2bf(acc[m][n][3]+bias_n[n]) };
            *(u16x4*)&SHT[col_loc*136 + tok_l] = v4;
          }
        }
      }
      __syncthreads();
      int d_loc = t>>2, qtr = t&3;
      int d = pass*64 + d_loc;
      int tok0 = R + qtr*32;
      long base;
      if (img) base = ((long)hd*128 + d)*2048 + tok0;
      else { int t2 = tok0 - rows_img; int b_ = t2>>9, s_ = t2&511;
             base = ((long)(b_*24+hd)*128 + d)*512 + s_; }
      #pragma unroll
      for (int k2=0;k2<4;k2++)
        *(u16x8*)(Vd + base + k2*8) = *(const u16x8*)&SHT[d_loc*136 + qtr*32 + k2*8];
    }
    return;
  }

  // ---- fused RMSNorm + RoPE epilogue (Q/K) ----
  float part[4][4];
  #pragma unroll
  for (int m=0;m<4;m++)
    #pragma unroll
    for (int r=0;r<4;r++){
      float s_ = 0.f;
      #pragma unroll
      for (int n=0;n<4;n++){ float v = acc[m][n][r] + bias_n[n]; s_ += v*v; }
      part[m][r] = s_;
    }
  #pragma unroll
  for (int m=0;m<4;m++)
    #pragma unroll
    for (int r=0;r<4;r++){
      part[m][r] += __shfl_xor(part[m][r], 1);
      part[m][r] += __shfl_xor(part[m][r], 2);
      part[m][r] += __shfl_xor(part[m][r], 4);
      part[m][r] += __shfl_xor(part[m][r], 8);
    }
  __syncthreads();                                   // staging reads done; reuse SH
  float* rs = (float*)SH;                            // [2 wc][2 wr][64 row]
  if (li == 0){
    #pragma unroll
    for (int m=0;m<4;m++)
      #pragma unroll
      for (int r=0;r<4;r++)
        rs[(wc*2+wr)*64 + m*16 + g*4 + r] = part[m][r];
  }
  __syncthreads();
  float fac[4][4];
  #pragma unroll
  for (int m=0;m<4;m++)
    #pragma unroll
    for (int r=0;r<4;r++){
      int idx = m*16 + g*4 + r;
      float tot = rs[(0*2+wr)*64 + idx] + rs[(1*2+wr)*64 + idx];
      fac[m][r] = rsqrtf(tot*(1.0f/128.0f) + 1e-6f);
    }

  const float* nw = (sec==0) ? (img ? nq_ : naq_) : (img ? nk_ : nak_);
  const float qs = (sec==0) ? (float)(0.08838834764831845 * 1.4426950408889634) : 1.0f;
  float nw_n[4];
  #pragma unroll
  for (int n=0;n<4;n++) nw_n[n] = nw[wc*64 + n*16 + li];

  unsigned short* Kd = img ? Kdi : Kde;

  #pragma unroll
  for (int m=0;m<4;m++){
    #pragma unroll
    for (int r=0;r<4;r++){
      int row_l = wr*64 + m*16 + g*4 + r;
      int t_row = R + row_l;
      int b_, s_, p_;
      if (img){ b_ = t_row>>10; s_ = t_row&1023; p_ = 512+s_; }
      else { int t2 = t_row - rows_img; b_ = t2>>9; s_ = t2&511; p_ = s_; }
      long didx;
      if (sec==0) didx = (long)(b_*24+hd)*1536 + (img ? 512+s_ : s_);
      else        didx = img ? ((long)hd*2048 + t_row) : ((long)(b_*24+hd)*512 + s_);
      const float* crow = cs + (long)p_*128;
      const float* srow = sn + (long)p_*128;
      unsigned short* drow = ((sec==0)?Qd:Kd) + didx*128;
      #pragma unroll
      for (int n=0;n<4;n++){
        int cl = wc*64 + n*16 + li;
        float x = (acc[m][n][r] + bias_n[n]) * fac[m][r] * nw_n[n];
        float xo = __shfl_xor(x, 1);
        float o_ = x*crow[cl] + ((l&1) ? xo*srow[cl] : -xo*srow[cl]);
        drow[cl] = f2bf(o_*qs);
      }
    }
  }
}

// ---------------- fused output GEMM (block-diagonal over rows) ----------------
__global__ __launch_bounds__(256) void k_gemmO(
    const unsigned short* __restrict__ X, const unsigned short* __restrict__ Wf,
    float* __restrict__ out, const float* __restrict__ bo, const float* __restrict__ bao)
{
  const int K = 3072;
  __shared__ unsigned short As[2][4096];
  __shared__ unsigned short Bs[2][4096];
  const int t = threadIdx.x, w = t>>6, l = t&63;
  const int bx = blockIdx.x, by = blockIdx.y;
  const bool enc = bx >= 16;
  const unsigned short* Wp = Wf + (enc ? 9437184 : 0);
  const float* bias = enc ? bao : bo;
  const int R = bx*128, C = by*128;
  long xbase, obase;
  if (!enc){ xbase = (long)(R>>10)*1536 + 512 + (R&1023); obase = (long)R*3072; }
  else { int Rp = R-2048; xbase = (long)(Rp>>9)*1536 + (Rp&511); obase = 6291456 + (long)Rp*3072; }
  const int wr = w>>1, wc = w&1;
  f32x4 acc[4][4] = {};

  auto stage = [&](int buf, int kt){
    const int k0 = kt*32;
    #pragma unroll
    for (int c=0;c<2;c++){
      int row = c*64 + (t>>2);
      int scol = ((t&3)<<3) ^ ((row&3)<<3) ^ (((row>>3)&1)<<4);
      gll16(X + (xbase+row)*K + k0 + scol, &As[buf][c*2048 + w*512]);
      gll16(Wp + (long)(C+row)*K + k0 + scol, &Bs[buf][c*2048 + w*512]);
    }
  };

  stage(0,0);
  int buf = 0;
  for (int kt=0; kt<96; kt++){
    __syncthreads();
    if (kt+1 < 96) stage(buf^1, kt+1);
    bf16x8 a[4], b[4];
    #pragma unroll
    for (int m=0;m<4;m++){
      int ar = wr*64 + m*16 + (l&15);
      int ac = ((l>>4)<<3) ^ ((ar&3)<<3) ^ (((ar>>3)&1)<<4);
      a[m] = *(const bf16x8*)&As[buf][ar*32 + ac];
      int br = wc*64 + m*16 + (l&15);
      int bc2 = ((l>>4)<<3) ^ ((br&3)<<3) ^ (((br>>3)&1)<<4);
      b[m] = *(const bf16x8*)&Bs[buf][br*32 + bc2];
    }
    #pragma unroll
    for (int m=0;m<4;m++)
      #pragma unroll
      for (int n=0;n<4;n++)
        acc[m][n] = __builtin_amdgcn_mfma_f32_16x16x32_bf16(a[m], b[n], acc[m][n], 0,0,0);
    buf ^= 1;
  }

  #pragma unroll
  for (int m=0;m<4;m++){
    int rl = wr*64 + m*16 + ((l>>4)<<2);
    #pragma unroll
    for (int n=0;n<4;n++){
      int col = C + wc*64 + n*16 + (l&15);
      float bvv = bias[col];
      #pragma unroll
      for (int r=0;r<4;r++)
        out[obase + (long)(rl+r)*3072 + col] = acc[m][n][r] + bvv;
    }
  }
}

// ---------------- flash attention (proven round-6/8/10 schedule) ----------------
__global__ __launch_bounds__(256) void k_attn(
    const unsigned short* __restrict__ Q,
    const unsigned short* __restrict__ Ke, const unsigned short* __restrict__ Ki,
    const unsigned short* __restrict__ Ve, const unsigned short* __restrict__ Vi,
    unsigned short* __restrict__ AO)
{
  __shared__ unsigned short Ks[8192];          // [64 kv][128 d], XOR-swizzled
  __shared__ unsigned short Vs[8192];          // [128 d][64 kv], XOR-swizzled
  __shared__ unsigned short Ps[4][1408];       // per-wave P tile [16 q][88 k-pad]
  const int t = threadIdx.x, w = t>>6, l = t&63;
  const int h = blockIdx.y, b = blockIdx.z;
  const int bh = b*24 + h;
  const int q0 = blockIdx.x*64 + w*16;
  const int g = l>>4;

  auto stageK = [&](int jt){
    const unsigned short* ksrc = (jt < 8) ? Ke + ((long)bh*512 + jt*64)*128
                                          : Ki + ((long)h*2048 + (jt-8)*64)*128;
    #pragma unroll
    for (int c=0;c<4;c++){
      int row = c*16 + (t>>4);
      int col = ((t&15)<<3) ^ ((row&7)<<3);
      gll16(ksrc + row*128 + col, &Ks[c*2048 + w*512]);
    }
  };
  auto stageV = [&](int jt){
    const unsigned short* vsrc; long vstr;
    if (jt < 8){ vsrc = Ve + (long)bh*65536 + jt*64; vstr = 512; }
    else { vsrc = Vi + (long)h*262144 + (jt-8)*64; vstr = 2048; }
    #pragma unroll
    for (int c=0;c<4;c++){
      int row = c*32 + (t>>3);
      int col = ((t&7)<<3) ^ ((row&7)<<3);
      gll16(vsrc + (long)row*vstr + col, &Vs[c*2048 + w*512]);
    }
  };

  bf16x8 qf[4];
  {
    const unsigned short* qp = Q + ((long)bh*1536 + q0 + (l&15))*128 + (g<<3);
    #pragma unroll
    for (int kc=0;kc<4;kc++) qf[kc] = *(const bf16x8*)(qp + kc*32);
  }
  f32x4 o[8] = {};
  float mx = -1e30f;
  float ls = 0.f;            // per-lane partial sum over own (q, k-slice)

  stageK(0);
  for (int jt=0; jt<40; jt++){
    __syncthreads();                 // K(jt) landed; all waves past PV(jt-1)
    stageV(jt);                      // covered by QK + softmax below

    // S^T tile: sf[ct][r] = S[q = q0 + (l&15)][k = ct*16 + g*4 + r]
    f32x4 sf[4];
    __builtin_amdgcn_s_setprio(1);
    #pragma unroll
    for (int ct=0;ct<4;ct++){
      f32x4 s = {};
      #pragma unroll
      for (int kc=0;kc<4;kc++){
        int krow = ct*16 + (l&15);
        int kcol = (kc*32 + (g<<3)) ^ ((krow&7)<<3);
        bf16x8 kb = *(const bf16x8*)&Ks[krow*128 + kcol];
        s = __builtin_amdgcn_mfma_f32_16x16x32_bf16(kb, qf[kc], s, 0,0,0);  // SWAPPED
      }
      sf[ct] = s;
    }
    __builtin_amdgcn_s_setprio(0);

    // per-lane slice max (own q); defer-max with THR=8 (log2 domain)
    float pm = sf[0][0];
    #pragma unroll
    for (int ct=0;ct<4;ct++)
      #pragma unroll
      for (int r=0;r<4;r++) pm = fmaxf(pm, sf[ct][r]);
    if (!__all(pm <= mx + 8.0f)){
      float tmax = pm;
      tmax = fmaxf(tmax, __shfl_xor(tmax, 16));
      tmax = fmaxf(tmax, __shfl_xor(tmax, 32));     // full-row max for own q
      float mn = fmaxf(mx, tmax);
      float al = exp2f(mx - mn);
      mx = mn;
      ls *= al;
      #pragma unroll
      for (int r=0;r<4;r++){
        float alo = __shfl(al, (l&48) | ((g<<2)+r));  // factor for o-row q' = 4g+r
        #pragma unroll
        for (int f=0;f<8;f++) o[f][r] *= alo;
      }
    }
    // P = exp2(S - mx), pack pairs, write b64; accumulate per-lane ls
    #pragma unroll
    for (int ct=0;ct<4;ct++){
      float p0 = exp2f(sf[ct][0]-mx), p1 = exp2f(sf[ct][1]-mx);
      float p2 = exp2f(sf[ct][2]-mx), p3 = exp2f(sf[ct][3]-mx);
      ls += (p0+p1)+(p2+p3);
      uint2v pk = { cvtpk(p0,p1), cvtpk(p2,p3) };
      *(uint2v*)&Ps[w][(l&15)*88 + ct*16 + (g<<2)] = pk;
    }
    __syncthreads();                 // V(jt) landed; all waves done reading Ks

    if (jt+1 < 40) stageK(jt+1);     // overwrites Ks; covered by PV below

    bf16x8 pa[2];
    #pragma unroll
    for (int kc=0;kc<2;kc++)
      pa[kc] = *(const bf16x8*)&Ps[w][(l&15)*88 + kc*32 + (g<<3)];
    __builtin_amdgcn_s_setprio(1);
    #pragma unroll
    for (int f=0;f<8;f++){
      #pragma unroll
      for (int kc=0;kc<2;kc++){
        int vrow = f*16 + (l&15);
        int vcol = (kc*32 + (g<<3)) ^ ((vrow&7)<<3);
        bf16x8 vb = *(const bf16x8*)&Vs[vrow*64 + vcol];
        o[f] = __builtin_amdgcn_mfma_f32_16x16x32_bf16(pa[kc], vb, o[f], 0,0,0);
      }
    }
    __builtin_amdgcn_s_setprio(0);
  }

  // finalize: full row-sum for own q, then fetch for o-rows q' = 4g+r
  ls += __shfl_xor(ls, 16);
  ls += __shfl_xor(ls, 32);
  #pragma unroll
  for (int r=0;r<4;r++){
    float lso = __shfl(ls, (l&48) | ((g<<2)+r));
    float inv = 1.0f/lso;
    int qrow = q0 + (g<<2) + r;
    #pragma unroll
    for (int f=0;f<8;f++){
      AO[((long)b*1536 + qrow)*3072 + h*128 + f*16 + (l&15)] = f2bf(o[f][r]*inv);
    }
  }
}

// ---------------- host launch ----------------
extern "C" void kernel_launch(void* const* d_in, const int* in_sizes, int n_in,
                              void* d_out, int out_size, void* d_ws, size_t ws_size,
                              hipStream_t stream)
{
  const float* hs  = (const float*)d_in[0];
  const float* ehs = (const float*)d_in[1];
  const float* rc  = (const float*)d_in[2];
  const float* rs_ = (const float*)d_in[3];
  const float* wq = (const float*)d_in[4];  const float* bq = (const float*)d_in[5];
  const float* wk = (const float*)d_in[6];  const float* bk = (const float*)d_in[7];
  const float* wv = (const float*)d_in[8];  const float* bv = (const float*)d_in[9];
  const float* waq= (const float*)d_in[10]; const float* baq= (const float*)d_in[11];
  const float* wak= (const float*)d_in[12]; const float* bak= (const float*)d_in[13];
  const float* wav= (const float*)d_in[14]; const float* bav= (const float*)d_in[15];
  const float* wo = (const float*)d_in[16]; const float* bo = (const float*)d_in[17];
  const float* wao= (const float*)d_in[18]; const float* bao= (const float*)d_in[19];
  const float* nq = (const float*)d_in[20]; const float* nk = (const float*)d_in[21];
  const float* naq= (const float*)d_in[22]; const float* nak= (const float*)d_in[23];

  char* p = (char*)d_ws;
  auto alloc = [&](size_t bytes){ char* r = p; p += bytes; return r; };

  if (ws_size >= (size_t)226492416){
    // ---------- main path (226.5 MB; 245.4 proven available in round 4) ----------
    unsigned short* Xh = (unsigned short*)alloc(12582912);  // [2048][3072]
    unsigned short* Xe = (unsigned short*)alloc(6291456);   // [1024][3072] (contiguous after Xh)
    unsigned short* Wb = (unsigned short*)alloc(150994944); // 8 weight slots bf16
    unsigned short* Qb = (unsigned short*)alloc(18874368);  // Q [2][24][1536][128]
    unsigned short* Ke = (unsigned short*)alloc(6291456);   // Kenc [2][24][512][128]
    unsigned short* Ki = (unsigned short*)alloc(12582912);  // Kimg [24][2048][128]
    unsigned short* Ve = (unsigned short*)alloc(6291456);   // Vtenc [2][24][128][512]
    unsigned short* Vi = (unsigned short*)alloc(12582912);  // Vtimg [24][128][2048]
    unsigned short* AO = Xh;                                // aliases Xh+Xe (dead by attn)
    (void)Xe;

    k_castX2<<<9216,256,0,stream>>>(hs, ehs, Xh);
    k_castW8<<<73728,256,0,stream>>>(wq, wk, wv, waq, wak, wav, wo, wao, Wb);

    // merged img+enc QKV GEMM (rows 0..2047 img, 2048..3071 enc)
    k_gemmP<<<dim3(24,72),256,0,stream>>>(Xh, Wb, Wb + (long)3*9437184,
                                          bq, bk, bv, baq, bak, bav,
                                          nq, nk, naq, nak, rc, rs_,
                                          Qb, Ki, Ke, Vi, Ve, 2048);

    k_attn<<<dim3(24,24,2),256,0,stream>>>(Qb, Ke, Ki, Ve, Vi, AO);

    k_gemmO<<<dim3(24,24),256,0,stream>>>(AO, Wb + (long)6*9437184, (float*)d_out, bo, bao);
  } else {
    // ---------- fallback path (132.1 MB): 3 weight slots, groups sequential ----------
    unsigned short* Xh = (unsigned short*)alloc(12582912);
    unsigned short* Xe = (unsigned short*)alloc(6291456);
    unsigned short* Wb = (unsigned short*)alloc(56623104);  // 3 slots
    unsigned short* Qb = (unsigned short*)alloc(18874368);
    unsigned short* Ke = (unsigned short*)alloc(6291456);
    unsigned short* Ki = (unsigned short*)alloc(12582912);
    unsigned short* Ve = (unsigned short*)alloc(6291456);
    unsigned short* Vi = (unsigned short*)alloc(12582912);
    unsigned short* AO = Xh;

    k_castX2<<<9216,256,0,stream>>>(hs, ehs, Xh);

    k_cast<<<9216,256,0,stream>>>(wq, Wb, 2359296);
    k_cast<<<9216,256,0,stream>>>(wk, Wb + 9437184, 2359296);
    k_cast<<<9216,256,0,stream>>>(wv, Wb + 18874368, 2359296);
    k_gemmP<<<dim3(16,72),256,0,stream>>>(Xh, Wb, Wb,
                                          bq, bk, bv, bq, bk, bv,
                                          nq, nk, nq, nk, rc, rs_,
                                          Qb, Ki, Ke, Vi, Ve, 1<<28);

    k_cast<<<9216,256,0,stream>>>(waq, Wb, 2359296);
    k_cast<<<9216,256,0,stream>>>(wak, Wb + 9437184, 2359296);
    k_cast<<<9216,256,0,stream>>>(wav, Wb + 18874368, 2359296);
    k_gemmP<<<dim3(8,72),256,0,stream>>>(Xe, Wb, Wb,
                                         baq, bak, bav, baq, bak, bav,
                                         naq, nak, naq, nak, rc, rs_,
                                         Qb, Ki, Ke, Vi, Ve, 0);

    k_attn<<<dim3(24,24,2),256,0,stream>>>(Qb, Ke, Ki, Ve, Vi, AO);

    k_castW2<<<18432,256,0,stream>>>(wo, wao, Wb);
    k_gemmO<<<dim3(24,24),256,0,stream>>>(AO, Wb, (float*)d_out, bo, bao);
  }
}

// Round 13
// 658.881 us; speedup vs baseline: 1.0835x; 1.0076x over previous
//
#include <hip/hip_runtime.h>

typedef __attribute__((ext_vector_type(8))) short bf16x8;
typedef __attribute__((ext_vector_type(8))) unsigned short u16x8;
typedef __attribute__((ext_vector_type(4))) unsigned short u16x4;
typedef __attribute__((ext_vector_type(4))) float f32x4;
typedef __attribute__((ext_vector_type(2))) unsigned uint2v;

#define DEV static __device__ __forceinline__

DEV unsigned short f2bf(float f){
  unsigned u = __float_as_uint(f);
  u += 0x7fff + ((u>>16)&1);
  return (unsigned short)(u>>16);
}
DEV float bf2f(unsigned short b){ return __uint_as_float(((unsigned)b)<<16); }
DEV unsigned cvtpk(float lo, float hi){
  unsigned r;
  asm("v_cvt_pk_bf16_f32 %0, %1, %2" : "=v"(r) : "v"(lo), "v"(hi));
  return r;
}

DEV void gll16(const void* g, void* l){
  __builtin_amdgcn_global_load_lds((__attribute__((address_space(1))) unsigned*)(void*)g,
                                   (__attribute__((address_space(3))) unsigned*)l, 16, 0, 0);
}

// ---------------- cast fp32 -> bf16 (vectorized) ----------------
__global__ void k_cast(const float* __restrict__ x, unsigned short* __restrict__ y, int n4){
  int i = blockIdx.x*256 + threadIdx.x;
  if (i >= n4) return;
  f32x4 v = ((const f32x4*)x)[i];
  u16x4 o = { f2bf(v.x), f2bf(v.y), f2bf(v.z), f2bf(v.w) };
  ((u16x4*)y)[i] = o;
}

// ---------------- 2-segment input cast (hs | ehs -> contiguous Xh,Xe) ----------------
__global__ void k_castX2(const float* __restrict__ s0, const float* __restrict__ s1,
                         unsigned short* __restrict__ y){
  unsigned i = blockIdx.x*256 + threadIdx.x;          // < 2359296
  const float* s = (i < 1572864u) ? s0 : s1;
  unsigned off = (i < 1572864u) ? i : i - 1572864u;
  f32x4 v = ((const f32x4*)s)[off];
  u16x4 o = { f2bf(v.x), f2bf(v.y), f2bf(v.z), f2bf(v.w) };
  ((u16x4*)y)[i] = o;
}

// ---------------- 8-segment weight cast (all weights, one launch) ----------------
__global__ void k_castW8(const float* __restrict__ s0, const float* __restrict__ s1,
                         const float* __restrict__ s2, const float* __restrict__ s3,
                         const float* __restrict__ s4, const float* __restrict__ s5,
                         const float* __restrict__ s6, const float* __restrict__ s7,
                         unsigned short* __restrict__ y){
  unsigned i = blockIdx.x*256 + threadIdx.x;          // < 8*2359296
  unsigned seg = i / 2359296u;                        // uniform per block
  unsigned off = i - seg*2359296u;
  const float* s = seg==0?s0: seg==1?s1: seg==2?s2: seg==3?s3:
                   seg==4?s4: seg==5?s5: seg==6?s6: s7;
  f32x4 v = ((const f32x4*)s)[off];
  u16x4 o = { f2bf(v.x), f2bf(v.y), f2bf(v.z), f2bf(v.w) };
  ((u16x4*)y)[i] = o;
}

// ---------------- 2-segment weight cast (fallback path) ----------------
__global__ void k_castW2(const float* __restrict__ s0, const float* __restrict__ s1,
                         unsigned short* __restrict__ y){
  unsigned i = blockIdx.x*256 + threadIdx.x;          // < 2*2359296
  unsigned seg = i / 2359296u;
  unsigned off = i - seg*2359296u;
  const float* s = seg==0?s0:s1;
  f32x4 v = ((const f32x4*)s)[off];
  u16x4 o = { f2bf(v.x), f2bf(v.y), f2bf(v.z), f2bf(v.w) };
  ((u16x4*)y)[i] = o;
}

// ---------------- merged QKV projection GEMM, fully fused epilogues ----------------
// XCD swizzle (nXg=1, nYg=8): each XCD owns ALL row-blocks x (gridDim.y/8) contiguous
// W-columns -> W panels fetched once chip-wide (fetch = X*8 + W*1 ~ 264 MB vs 495).
__global__ __launch_bounds__(256) void k_gemmP(
    const unsigned short* __restrict__ X,
    const unsigned short* __restrict__ Wimg, const unsigned short* __restrict__ Wenc,
    const float* __restrict__ b0, const float* __restrict__ b1, const float* __restrict__ b2,
    const float* __restrict__ b3, const float* __restrict__ b4, const float* __restrict__ b5,
    const float* __restrict__ nq_, const float* __restrict__ nk_,
    const float* __restrict__ naq_, const float* __restrict__ nak_,
    const float* __restrict__ cs, const float* __restrict__ sn,
    unsigned short* __restrict__ Qd,
    unsigned short* __restrict__ Kdi, unsigned short* __restrict__ Kde,
    unsigned short* __restrict__ Vdi, unsigned short* __restrict__ Vde,
    int rows_img)
{
  const int K = 3072;
  __shared__ unsigned short SH[16384];                // exactly 32768 B
  unsigned short (*As)[4096] = (unsigned short(*)[4096])SH;
  unsigned short (*Bs)[4096] = (unsigned short(*)[4096])(SH + 8192);
  const int t = threadIdx.x, w = t>>6, l = t&63;
  const int li = l&15, g = l>>4;
  // XCD-chunked decode: hw XCD = linear_id % 8
  unsigned wid = blockIdx.x + gridDim.x*blockIdx.y;
  unsigned xc = wid & 7, ii = wid >> 3;
  unsigned nbx = gridDim.x;
  int by = (int)(xc*(gridDim.y>>3) + ii/nbx);
  int bx = (int)(ii % nbx);
  const int sec = by>=48 ? 2 : (by>=24 ? 1 : 0);
  const int hd = by - sec*24;
  const int Cl = hd*128;
  const int R = bx*128;
  const bool img = (R < rows_img);                    // block-uniform
  const unsigned short* Wp = (img ? Wimg : Wenc) + (long)sec*9437184 + (long)Cl*K;
  const float* bias = img ? ((sec==0)?b0:(sec==1)?b1:b2)
                          : ((sec==0)?b3:(sec==1)?b4:b5);
  const int wr = w>>1, wc = w&1;
  f32x4 acc[4][4] = {};

  auto stage = [&](int buf, int kt){
    const int k0 = kt*32;
    #pragma unroll
    for (int c=0;c<2;c++){
      int row = c*64 + (t>>2);
      int scol = ((t&3)<<3) ^ ((row&3)<<3) ^ (((row>>3)&1)<<4);
      gll16(X + (long)(R+row)*K + k0 + scol, &As[buf][c*2048 + w*512]);
      gll16(Wp + (long)row*K + k0 + scol, &Bs[buf][c*2048 + w*512]);
    }
  };

  stage(0,0);
  int buf = 0;
  for (int kt=0; kt<96; kt++){
    __syncthreads();
    if (kt+1 < 96) stage(buf^1, kt+1);
    bf16x8 a[4], b[4];
    #pragma unroll
    for (int m=0;m<4;m++){
      int ar = wr*64 + m*16 + li;
      int ac = (g<<3) ^ ((ar&3)<<3) ^ (((ar>>3)&1)<<4);
      a[m] = *(const bf16x8*)&As[buf][ar*32 + ac];
      int br = wc*64 + m*16 + li;
      int bc2 = (g<<3) ^ ((br&3)<<3) ^ (((br>>3)&1)<<4);
      b[m] = *(const bf16x8*)&Bs[buf][br*32 + bc2];
    }
    #pragma unroll
    for (int m=0;m<4;m++)
      #pragma unroll
      for (int n=0;n<4;n++)
        acc[m][n] = __builtin_amdgcn_mfma_f32_16x16x32_bf16(a[m], b[n], acc[m][n], 0,0,0);
    buf ^= 1;
  }

  float bias_n[4];
  #pragma unroll
  for (int n=0;n<4;n++) bias_n[n] = bias[Cl + wc*64 + n*16 + li];

  if (sec == 2){
    // ---- V: 2-pass LDS-transpose epilogue (SHT[64 d][136 tok]) ----
    unsigned short* SHT = SH;
    unsigned short* Vd = img ? Vdi : Vde;
    #pragma unroll
    for (int pass=0; pass<2; pass++){
      __syncthreads();                               // staging / prev-pass reads done
      if (wc == pass){
        #pragma unroll
        for (int m=0;m<4;m++){
          int tok_l = wr*64 + m*16 + (g<<2);
          #pragma unroll
          for (int n=0;n<4;n++){
            int col_loc = n*16 + li;                 // 0..63 within this pass
            u16x4 v4 = { f2bf(acc[m][n][0]+bias_n[n]), f2bf(acc[m][n][1]+bias_n[n]),
                         f2bf(acc[m][n][2]+bias_n[n]), f2bf(acc[m][n][3]+bias_n[n]) };
            *(u16x4*)&SHT[col_loc*136 + tok_l] = v4;
          }
        }
      }
      __syncthreads();
      int d_loc = t>>2, qtr = t&3;
      int d = pass*64 + d_loc;
      int tok0 = R + qtr*32;
      long base;
      if (img) base = ((long)hd*128 + d)*2048 + tok0;
      else { int t2 = tok0 - rows_img; int b_ = t2>>9, s_ = t2&511;
             base = ((long)(b_*24+hd)*128 + d)*512 + s_; }
      #pragma unroll
      for (int k2=0;k2<4;k2++)
        *(u16x8*)(Vd + base + k2*8) = *(const u16x8*)&SHT[d_loc*136 + qtr*32 + k2*8];
    }
    return;
  }

  // ---- fused RMSNorm + RoPE epilogue (Q/K) ----
  float part[4][4];
  #pragma unroll
  for (int m=0;m<4;m++)
    #pragma unroll
    for (int r=0;r<4;r++){
      float s_ = 0.f;
      #pragma unroll
      for (int n=0;n<4;n++){ float v = acc[m][n][r] + bias_n[n]; s_ += v*v; }
      part[m][r] = s_;
    }
  #pragma unroll
  for (int m=0;m<4;m++)
    #pragma unroll
    for (int r=0;r<4;r++){
      part[m][r] += __shfl_xor(part[m][r], 1);
      part[m][r] += __shfl_xor(part[m][r], 2);
      part[m][r] += __shfl_xor(part[m][r], 4);
      part[m][r] += __shfl_xor(part[m][r], 8);
    }
  __syncthreads();                                   // staging reads done; reuse SH
  float* rs = (float*)SH;                            // [2 wc][2 wr][64 row]
  if (li == 0){
    #pragma unroll
    for (int m=0;m<4;m++)
      #pragma unroll
      for (int r=0;r<4;r++)
        rs[(wc*2+wr)*64 + m*16 + g*4 + r] = part[m][r];
  }
  __syncthreads();
  float fac[4][4];
  #pragma unroll
  for (int m=0;m<4;m++)
    #pragma unroll
    for (int r=0;r<4;r++){
      int idx = m*16 + g*4 + r;
      float tot = rs[(0*2+wr)*64 + idx] + rs[(1*2+wr)*64 + idx];
      fac[m][r] = rsqrtf(tot*(1.0f/128.0f) + 1e-6f);
    }

  const float* nw = (sec==0) ? (img ? nq_ : naq_) : (img ? nk_ : nak_);
  const float qs = (sec==0) ? (float)(0.08838834764831845 * 1.4426950408889634) : 1.0f;
  float nw_n[4];
  #pragma unroll
  for (int n=0;n<4;n++) nw_n[n] = nw[wc*64 + n*16 + li];

  unsigned short* Kd = img ? Kdi : Kde;

  #pragma unroll
  for (int m=0;m<4;m++){
    #pragma unroll
    for (int r=0;r<4;r++){
      int row_l = wr*64 + m*16 + g*4 + r;
      int t_row = R + row_l;
      int b_, s_, p_;
      if (img){ b_ = t_row>>10; s_ = t_row&1023; p_ = 512+s_; }
      else { int t2 = t_row - rows_img; b_ = t2>>9; s_ = t2&511; p_ = s_; }
      long didx;
      if (sec==0) didx = (long)(b_*24+hd)*1536 + (img ? 512+s_ : s_);
      else        didx = img ? ((long)hd*2048 + t_row) : ((long)(b_*24+hd)*512 + s_);
      const float* crow = cs + (long)p_*128;
      const float* srow = sn + (long)p_*128;
      unsigned short* drow = ((sec==0)?Qd:Kd) + didx*128;
      #pragma unroll
      for (int n=0;n<4;n++){
        int cl = wc*64 + n*16 + li;
        float x = (acc[m][n][r] + bias_n[n]) * fac[m][r] * nw_n[n];
        float xo = __shfl_xor(x, 1);
        float o_ = x*crow[cl] + ((l&1) ? xo*srow[cl] : -xo*srow[cl]);
        drow[cl] = f2bf(o_*qs);
      }
    }
  }
}

// ---------------- fused output GEMM (block-diagonal over rows) ----------------
// XCD swizzle 2D (2 x-groups, 4 y-groups): fetch = 18.9*(2+4) ~ 113 MB vs 170.
__global__ __launch_bounds__(256) void k_gemmO(
    const unsigned short* __restrict__ X, const unsigned short* __restrict__ Wf,
    float* __restrict__ out, const float* __restrict__ bo, const float* __restrict__ bao)
{
  const int K = 3072;
  __shared__ unsigned short As[2][4096];
  __shared__ unsigned short Bs[2][4096];
  const int t = threadIdx.x, w = t>>6, l = t&63;
  // decode: grid (24,24); hw XCD = wid%8 = xg + 2*yg
  unsigned wid = blockIdx.x + 24u*blockIdx.y;
  unsigned xc = wid & 7, ii = wid >> 3;              // ii in [0,72)
  unsigned xg = xc & 1, yg = xc >> 1;
  int bx = (int)(xg*12 + ii%12);
  int by = (int)(yg*6 + ii/12);
  const bool enc = bx >= 16;
  const unsigned short* Wp = Wf + (enc ? 9437184 : 0);
  const float* bias = enc ? bao : bo;
  const int R = bx*128, C = by*128;
  long xbase, obase;
  if (!enc){ xbase = (long)(R>>10)*1536 + 512 + (R&1023); obase = (long)R*3072; }
  else { int Rp = R-2048; xbase = (long)(Rp>>9)*1536 + (Rp&511); obase = 6291456 + (long)Rp*3072; }
  const int wr = w>>1, wc = w&1;
  f32x4 acc[4][4] = {};

  auto stage = [&](int buf, int kt){
    const int k0 = kt*32;
    #pragma unroll
    for (int c=0;c<2;c++){
      int row = c*64 + (t>>2);
      int scol = ((t&3)<<3) ^ ((row&3)<<3) ^ (((row>>3)&1)<<4);
      gll16(X + (xbase+row)*K + k0 + scol, &As[buf][c*2048 + w*512]);
      gll16(Wp + (long)(C+row)*K + k0 + scol, &Bs[buf][c*2048 + w*512]);
    }
  };

  stage(0,0);
  int buf = 0;
  for (int kt=0; kt<96; kt++){
    __syncthreads();
    if (kt+1 < 96) stage(buf^1, kt+1);
    bf16x8 a[4], b[4];
    #pragma unroll
    for (int m=0;m<4;m++){
      int ar = wr*64 + m*16 + (l&15);
      int ac = ((l>>4)<<3) ^ ((ar&3)<<3) ^ (((ar>>3)&1)<<4);
      a[m] = *(const bf16x8*)&As[buf][ar*32 + ac];
      int br = wc*64 + m*16 + (l&15);
      int bc2 = ((l>>4)<<3) ^ ((br&3)<<3) ^ (((br>>3)&1)<<4);
      b[m] = *(const bf16x8*)&Bs[buf][br*32 + bc2];
    }
    #pragma unroll
    for (int m=0;m<4;m++)
      #pragma unroll
      for (int n=0;n<4;n++)
        acc[m][n] = __builtin_amdgcn_mfma_f32_16x16x32_bf16(a[m], b[n], acc[m][n], 0,0,0);
    buf ^= 1;
  }

  #pragma unroll
  for (int m=0;m<4;m++){
    int rl = wr*64 + m*16 + ((l>>4)<<2);
    #pragma unroll
    for (int n=0;n<4;n++){
      int col = C + wc*64 + n*16 + (l&15);
      float bvv = bias[col];
      #pragma unroll
      for (int r=0;r<4;r++)
        out[obase + (long)(rl+r)*3072 + col] = acc[m][n][r] + bvv;
    }
  }
}

// ---------------- flash attention (proven schedule + h-chunked XCD swizzle) ----------------
// Each XCD owns 3 heads -> its KV working set (~3.9 MB) fits the 4 MB per-XCD L2.
__global__ __launch_bounds__(256) void k_attn(
    const unsigned short* __restrict__ Q,
    const unsigned short* __restrict__ Ke, const unsigned short* __restrict__ Ki,
    const unsigned short* __restrict__ Ve, const unsigned short* __restrict__ Vi,
    unsigned short* __restrict__ AO)
{
  __shared__ unsigned short Ks[8192];          // [64 kv][128 d], XOR-swizzled
  __shared__ unsigned short Vs[8192];          // [128 d][64 kv], XOR-swizzled
  __shared__ unsigned short Ps[4][1408];       // per-wave P tile [16 q][88 k-pad]
  const int t = threadIdx.x, w = t>>6, l = t&63;
  // decode: grid (24,24,2); hw XCD = wid%8 owns heads [3*xc, 3*xc+3)
  unsigned wid = blockIdx.x + 24u*blockIdx.y + 576u*blockIdx.z;
  unsigned xc = wid & 7, ii = wid >> 3;              // ii in [0,144)
  int h = (int)(xc*3 + ii/48);
  unsigned rem = ii % 48;
  int b = (int)(rem/24);
  int qx = (int)(rem%24);
  const int bh = b*24 + h;
  const int q0 = qx*64 + w*16;
  const int g = l>>4;

  auto stageK = [&](int jt){
    const unsigned short* ksrc = (jt < 8) ? Ke + ((long)bh*512 + jt*64)*128
                                          : Ki + ((long)h*2048 + (jt-8)*64)*128;
    #pragma unroll
    for (int c=0;c<4;c++){
      int row = c*16 + (t>>4);
      int col = ((t&15)<<3) ^ ((row&7)<<3);
      gll16(ksrc + row*128 + col, &Ks[c*2048 + w*512]);
    }
  };
  auto stageV = [&](int jt){
    const unsigned short* vsrc; long vstr;
    if (jt < 8){ vsrc = Ve + (long)bh*65536 + jt*64; vstr = 512; }
    else { vsrc = Vi + (long)h*262144 + (jt-8)*64; vstr = 2048; }
    #pragma unroll
    for (int c=0;c<4;c++){
      int row = c*32 + (t>>3);
      int col = ((t&7)<<3) ^ ((row&7)<<3);
      gll16(vsrc + (long)row*vstr + col, &Vs[c*2048 + w*512]);
    }
  };

  bf16x8 qf[4];
  {
    const unsigned short* qp = Q + ((long)bh*1536 + q0 + (l&15))*128 + (g<<3);
    #pragma unroll
    for (int kc=0;kc<4;kc++) qf[kc] = *(const bf16x8*)(qp + kc*32);
  }
  f32x4 o[8] = {};
  float mx = -1e30f;
  float ls = 0.f;            // per-lane partial sum over own (q, k-slice)

  stageK(0);
  for (int jt=0; jt<40; jt++){
    __syncthreads();                 // K(jt) landed; all waves past PV(jt-1)
    stageV(jt);                      // covered by QK + softmax below

    // S^T tile: sf[ct][r] = S[q = q0 + (l&15)][k = ct*16 + g*4 + r]
    f32x4 sf[4];
    __builtin_amdgcn_s_setprio(1);
    #pragma unroll
    for (int ct=0;ct<4;ct++){
      f32x4 s = {};
      #pragma unroll
      for (int kc=0;kc<4;kc++){
        int krow = ct*16 + (l&15);
        int kcol = (kc*32 + (g<<3)) ^ ((krow&7)<<3);
        bf16x8 kb = *(const bf16x8*)&Ks[krow*128 + kcol];
        s = __builtin_amdgcn_mfma_f32_16x16x32_bf16(kb, qf[kc], s, 0,0,0);  // SWAPPED
      }
      sf[ct] = s;
    }
    __builtin_amdgcn_s_setprio(0);

    // per-lane slice max (own q); defer-max with THR=8 (log2 domain)
    float pm = sf[0][0];
    #pragma unroll
    for (int ct=0;ct<4;ct++)
      #pragma unroll
      for (int r=0;r<4;r++) pm = fmaxf(pm, sf[ct][r]);
    if (!__all(pm <= mx + 8.0f)){
      float tmax = pm;
      tmax = fmaxf(tmax, __shfl_xor(tmax, 16));
      tmax = fmaxf(tmax, __shfl_xor(tmax, 32));     // full-row max for own q
      float mn = fmaxf(mx, tmax);
      float al = exp2f(mx - mn);
      mx = mn;
      ls *= al;
      #pragma unroll
      for (int r=0;r<4;r++){
        float alo = __shfl(al, (l&48) | ((g<<2)+r));  // factor for o-row q' = 4g+r
        #pragma unroll
        for (int f=0;f<8;f++) o[f][r] *= alo;
      }
    }
    // P = exp2(S - mx), pack pairs, write b64; accumulate per-lane ls
    #pragma unroll
    for (int ct=0;ct<4;ct++){
      float p0 = exp2f(sf[ct][0]-mx), p1 = exp2f(sf[ct][1]-mx);
      float p2 = exp2f(sf[ct][2]-mx), p3 = exp2f(sf[ct][3]-mx);
      ls += (p0+p1)+(p2+p3);
      uint2v pk = { cvtpk(p0,p1), cvtpk(p2,p3) };
      *(uint2v*)&Ps[w][(l&15)*88 + ct*16 + (g<<2)] = pk;
    }
    __syncthreads();                 // V(jt) landed; all waves done reading Ks

    if (jt+1 < 40) stageK(jt+1);     // overwrites Ks; covered by PV below

    bf16x8 pa[2];
    #pragma unroll
    for (int kc=0;kc<2;kc++)
      pa[kc] = *(const bf16x8*)&Ps[w][(l&15)*88 + kc*32 + (g<<3)];
    __builtin_amdgcn_s_setprio(1);
    #pragma unroll
    for (int f=0;f<8;f++){
      #pragma unroll
      for (int kc=0;kc<2;kc++){
        int vrow = f*16 + (l&15);
        int vcol = (kc*32 + (g<<3)) ^ ((vrow&7)<<3);
        bf16x8 vb = *(const bf16x8*)&Vs[vrow*64 + vcol];
        o[f] = __builtin_amdgcn_mfma_f32_16x16x32_bf16(pa[kc], vb, o[f], 0,0,0);
      }
    }
    __builtin_amdgcn_s_setprio(0);
  }

  // finalize: full row-sum for own q, then fetch for o-rows q' = 4g+r
  ls += __shfl_xor(ls, 16);
  ls += __shfl_xor(ls, 32);
  #pragma unroll
  for (int r=0;r<4;r++){
    float lso = __shfl(ls, (l&48) | ((g<<2)+r));
    float inv = 1.0f/lso;
    int qrow = q0 + (g<<2) + r;
    #pragma unroll
    for (int f=0;f<8;f++){
      AO[((long)b*1536 + qrow)*3072 + h*128 + f*16 + (l&15)] = f2bf(o[f][r]*inv);
    }
  }
}

// ---------------- host launch ----------------
extern "C" void kernel_launch(void* const* d_in, const int* in_sizes, int n_in,
                              void* d_out, int out_size, void* d_ws, size_t ws_size,
                              hipStream_t stream)
{
  const float* hs  = (const float*)d_in[0];
  const float* ehs = (const float*)d_in[1];
  const float* rc  = (const float*)d_in[2];
  const float* rs_ = (const float*)d_in[3];
  const float* wq = (const float*)d_in[4];  const float* bq = (const float*)d_in[5];
  const float* wk = (const float*)d_in[6];  const float* bk = (const float*)d_in[7];
  const float* wv = (const float*)d_in[8];  const float* bv = (const float*)d_in[9];
  const float* waq= (const float*)d_in[10]; const float* baq= (const float*)d_in[11];
  const float* wak= (const float*)d_in[12]; const float* bak= (const float*)d_in[13];
  const float* wav= (const float*)d_in[14]; const float* bav= (const float*)d_in[15];
  const float* wo = (const float*)d_in[16]; const float* bo = (const float*)d_in[17];
  const float* wao= (const float*)d_in[18]; const float* bao= (const float*)d_in[19];
  const float* nq = (const float*)d_in[20]; const float* nk = (const float*)d_in[21];
  const float* naq= (const float*)d_in[22]; const float* nak= (const float*)d_in[23];

  char* p = (char*)d_ws;
  auto alloc = [&](size_t bytes){ char* r = p; p += bytes; return r; };

  if (ws_size >= (size_t)226492416){
    // ---------- main path (226.5 MB; 245.4 proven available in round 4) ----------
    unsigned short* Xh = (unsigned short*)alloc(12582912);  // [2048][3072]
    unsigned short* Xe = (unsigned short*)alloc(6291456);   // [1024][3072] (contiguous after Xh)
    unsigned short* Wb = (unsigned short*)alloc(150994944); // 8 weight slots bf16
    unsigned short* Qb = (unsigned short*)alloc(18874368);  // Q [2][24][1536][128]
    unsigned short* Ke = (unsigned short*)alloc(6291456);   // Kenc [2][24][512][128]
    unsigned short* Ki = (unsigned short*)alloc(12582912);  // Kimg [24][2048][128]
    unsigned short* Ve = (unsigned short*)alloc(6291456);   // Vtenc [2][24][128][512]
    unsigned short* Vi = (unsigned short*)alloc(12582912);  // Vtimg [24][128][2048]
    unsigned short* AO = Xh;                                // aliases Xh+Xe (dead by attn)
    (void)Xe;

    k_castX2<<<9216,256,0,stream>>>(hs, ehs, Xh);
    k_castW8<<<73728,256,0,stream>>>(wq, wk, wv, waq, wak, wav, wo, wao, Wb);

    // merged img+enc QKV GEMM (rows 0..2047 img, 2048..3071 enc)
    k_gemmP<<<dim3(24,72),256,0,stream>>>(Xh, Wb, Wb + (long)3*9437184,
                                          bq, bk, bv, baq, bak, bav,
                                          nq, nk, naq, nak, rc, rs_,
                                          Qb, Ki, Ke, Vi, Ve, 2048);

    k_attn<<<dim3(24,24,2),256,0,stream>>>(Qb, Ke, Ki, Ve, Vi, AO);

    k_gemmO<<<dim3(24,24),256,0,stream>>>(AO, Wb + (long)6*9437184, (float*)d_out, bo, bao);
  } else {
    // ---------- fallback path (132.1 MB): 3 weight slots, groups sequential ----------
    unsigned short* Xh = (unsigned short*)alloc(12582912);
    unsigned short* Xe = (unsigned short*)alloc(6291456);
    unsigned short* Wb = (unsigned short*)alloc(56623104);  // 3 slots
    unsigned short* Qb = (unsigned short*)alloc(18874368);
    unsigned short* Ke = (unsigned short*)alloc(6291456);
    unsigned short* Ki = (unsigned short*)alloc(12582912);
    unsigned short* Ve = (unsigned short*)alloc(6291456);
    unsigned short* Vi = (unsigned short*)alloc(12582912);
    unsigned short* AO = Xh;

    k_castX2<<<9216,256,0,stream>>>(hs, ehs, Xh);

    k_cast<<<9216,256,0,stream>>>(wq, Wb, 2359296);
    k_cast<<<9216,256,0,stream>>>(wk, Wb + 9437184, 2359296);
    k_cast<<<9216,256,0,stream>>>(wv, Wb + 18874368, 2359296);
    k_gemmP<<<dim3(16,72),256,0,stream>>>(Xh, Wb, Wb,
                                          bq, bk, bv, bq, bk, bv,
                                          nq, nk, nq, nk, rc, rs_,
                                          Qb, Ki, Ke, Vi, Ve, 1<<28);

    k_cast<<<9216,256,0,stream>>>(waq, Wb, 2359296);
    k_cast<<<9216,256,0,stream>>>(wak, Wb + 9437184, 2359296);
    k_cast<<<9216,256,0,stream>>>(wav, Wb + 18874368, 2359296);
    k_gemmP<<<dim3(8,72),256,0,stream>>>(Xe, Wb, Wb,
                                         baq, bak, bav, baq, bak, bav,
                                         naq, nak, naq, nak, rc, rs_,
                                         Qb, Ki, Ke, Vi, Ve, 0);

    k_attn<<<dim3(24,24,2),256,0,stream>>>(Qb, Ke, Ki, Ve, Vi, AO);

    k_castW2<<<18432,256,0,stream>>>(wo, wao, Wb);
    k_gemmO<<<dim3(24,24),256,0,stream>>>(AO, Wb, (float*)d_out, bo, bao);
  }
}

// Round 14
// 653.850 us; speedup vs baseline: 1.0918x; 1.0077x over previous
//
#include <hip/hip_runtime.h>

typedef __attribute__((ext_vector_type(8))) short bf16x8;
typedef __attribute__((ext_vector_type(8))) unsigned short u16x8;
typedef __attribute__((ext_vector_type(4))) unsigned short u16x4;
typedef __attribute__((ext_vector_type(4))) float f32x4;
typedef __attribute__((ext_vector_type(2))) unsigned uint2v;

#define DEV static __device__ __forceinline__

DEV unsigned short f2bf(float f){
  unsigned u = __float_as_uint(f);
  u += 0x7fff + ((u>>16)&1);
  return (unsigned short)(u>>16);
}
DEV float bf2f(unsigned short b){ return __uint_as_float(((unsigned)b)<<16); }
DEV unsigned cvtpk(float lo, float hi){
  unsigned r;
  asm("v_cvt_pk_bf16_f32 %0, %1, %2" : "=v"(r) : "v"(lo), "v"(hi));
  return r;
}

DEV void gll16(const void* g, void* l){
  __builtin_amdgcn_global_load_lds((__attribute__((address_space(1))) unsigned*)(void*)g,
                                   (__attribute__((address_space(3))) unsigned*)l, 16, 0, 0);
}

// ---------------- cast fp32 -> bf16 (vectorized) ----------------
__global__ void k_cast(const float* __restrict__ x, unsigned short* __restrict__ y, int n4){
  int i = blockIdx.x*256 + threadIdx.x;
  if (i >= n4) return;
  f32x4 v = ((const f32x4*)x)[i];
  u16x4 o = { f2bf(v.x), f2bf(v.y), f2bf(v.z), f2bf(v.w) };
  ((u16x4*)y)[i] = o;
}

// ---------------- 2-segment input cast (fallback path) ----------------
__global__ void k_castX2(const float* __restrict__ s0, const float* __restrict__ s1,
                         unsigned short* __restrict__ y){
  unsigned i = blockIdx.x*256 + threadIdx.x;          // < 2359296
  const float* s = (i < 1572864u) ? s0 : s1;
  unsigned off = (i < 1572864u) ? i : i - 1572864u;
  f32x4 v = ((const f32x4*)s)[off];
  u16x4 o = { f2bf(v.x), f2bf(v.y), f2bf(v.z), f2bf(v.w) };
  ((u16x4*)y)[i] = o;
}

// ---------------- unified cast: 8 weight segs -> Wb, then hs|ehs -> Xc ----------------
__global__ void k_castAll(const float* __restrict__ s0, const float* __restrict__ s1,
                          const float* __restrict__ s2, const float* __restrict__ s3,
                          const float* __restrict__ s4, const float* __restrict__ s5,
                          const float* __restrict__ s6, const float* __restrict__ s7,
                          const float* __restrict__ xh, const float* __restrict__ xe,
                          unsigned short* __restrict__ Wb, unsigned short* __restrict__ Xc){
  unsigned i = blockIdx.x*256 + threadIdx.x;          // < 8*2359296 + 2359296
  const float* s; unsigned off; unsigned short* dst; unsigned di;
  if (i < 18874368u){
    unsigned seg = i / 2359296u;                      // block-uniform
    off = i - seg*2359296u;
    s = seg==0?s0: seg==1?s1: seg==2?s2: seg==3?s3:
        seg==4?s4: seg==5?s5: seg==6?s6: s7;
    dst = Wb; di = i;
  } else {
    unsigned j = i - 18874368u;                       // < 2359296
    s = (j < 1572864u) ? xh : xe;
    off = (j < 1572864u) ? j : j - 1572864u;
    dst = Xc; di = j;
  }
  f32x4 v = ((const f32x4*)s)[off];
  u16x4 o = { f2bf(v.x), f2bf(v.y), f2bf(v.z), f2bf(v.w) };
  ((u16x4*)dst)[di] = o;
}

// ---------------- 2-segment weight cast (fallback path) ----------------
__global__ void k_castW2(const float* __restrict__ s0, const float* __restrict__ s1,
                         unsigned short* __restrict__ y){
  unsigned i = blockIdx.x*256 + threadIdx.x;          // < 2*2359296
  unsigned seg = i / 2359296u;
  unsigned off = i - seg*2359296u;
  const float* s = seg==0?s0:s1;
  f32x4 v = ((const f32x4*)s)[off];
  u16x4 o = { f2bf(v.x), f2bf(v.y), f2bf(v.z), f2bf(v.w) };
  ((u16x4*)y)[i] = o;
}

// ---------------- merged QKV projection GEMM, fully fused epilogues ----------------
// NATURAL block mapping (round-12 proven; round-13's XCD remap blew per-XCD L2
// working set: FETCH 495->516 MB, dur +8.5 us — reverted).
__global__ __launch_bounds__(256) void k_gemmP(
    const unsigned short* __restrict__ X,
    const unsigned short* __restrict__ Wimg, const unsigned short* __restrict__ Wenc,
    const float* __restrict__ b0, const float* __restrict__ b1, const float* __restrict__ b2,
    const float* __restrict__ b3, const float* __restrict__ b4, const float* __restrict__ b5,
    const float* __restrict__ nq_, const float* __restrict__ nk_,
    const float* __restrict__ naq_, const float* __restrict__ nak_,
    const float* __restrict__ cs, const float* __restrict__ sn,
    unsigned short* __restrict__ Qd,
    unsigned short* __restrict__ Kdi, unsigned short* __restrict__ Kde,
    unsigned short* __restrict__ Vdi, unsigned short* __restrict__ Vde,
    int rows_img)
{
  const int K = 3072;
  __shared__ unsigned short SH[16384];                // exactly 32768 B
  unsigned short (*As)[4096] = (unsigned short(*)[4096])SH;
  unsigned short (*Bs)[4096] = (unsigned short(*)[4096])(SH + 8192);
  const int t = threadIdx.x, w = t>>6, l = t&63;
  const int li = l&15, g = l>>4;
  const int by = blockIdx.y, bx = blockIdx.x;
  const int sec = by>=48 ? 2 : (by>=24 ? 1 : 0);
  const int hd = by - sec*24;
  const int Cl = hd*128;
  const int R = bx*128;
  const bool img = (R < rows_img);                    // block-uniform
  const unsigned short* Wp = (img ? Wimg : Wenc) + (long)sec*9437184 + (long)Cl*K;
  const float* bias = img ? ((sec==0)?b0:(sec==1)?b1:b2)
                          : ((sec==0)?b3:(sec==1)?b4:b5);
  const int wr = w>>1, wc = w&1;
  f32x4 acc[4][4] = {};

  auto stage = [&](int buf, int kt){
    const int k0 = kt*32;
    #pragma unroll
    for (int c=0;c<2;c++){
      int row = c*64 + (t>>2);
      int scol = ((t&3)<<3) ^ ((row&3)<<3) ^ (((row>>3)&1)<<4);
      gll16(X + (long)(R+row)*K + k0 + scol, &As[buf][c*2048 + w*512]);
      gll16(Wp + (long)row*K + k0 + scol, &Bs[buf][c*2048 + w*512]);
    }
  };

  stage(0,0);
  int buf = 0;
  for (int kt=0; kt<96; kt++){
    __syncthreads();
    if (kt+1 < 96) stage(buf^1, kt+1);
    bf16x8 a[4], b[4];
    #pragma unroll
    for (int m=0;m<4;m++){
      int ar = wr*64 + m*16 + li;
      int ac = (g<<3) ^ ((ar&3)<<3) ^ (((ar>>3)&1)<<4);
      a[m] = *(const bf16x8*)&As[buf][ar*32 + ac];
      int br = wc*64 + m*16 + li;
      int bc2 = (g<<3) ^ ((br&3)<<3) ^ (((br>>3)&1)<<4);
      b[m] = *(const bf16x8*)&Bs[buf][br*32 + bc2];
    }
    #pragma unroll
    for (int m=0;m<4;m++)
      #pragma unroll
      for (int n=0;n<4;n++)
        acc[m][n] = __builtin_amdgcn_mfma_f32_16x16x32_bf16(a[m], b[n], acc[m][n], 0,0,0);
    buf ^= 1;
  }

  float bias_n[4];
  #pragma unroll
  for (int n=0;n<4;n++) bias_n[n] = bias[Cl + wc*64 + n*16 + li];

  if (sec == 2){
    // ---- V: 2-pass LDS-transpose epilogue (SHT[64 d][136 tok]) ----
    unsigned short* SHT = SH;
    unsigned short* Vd = img ? Vdi : Vde;
    #pragma unroll
    for (int pass=0; pass<2; pass++){
      __syncthreads();                               // staging / prev-pass reads done
      if (wc == pass){
        #pragma unroll
        for (int m=0;m<4;m++){
          int tok_l = wr*64 + m*16 + (g<<2);
          #pragma unroll
          for (int n=0;n<4;n++){
            int col_loc = n*16 + li;                 // 0..63 within this pass
            u16x4 v4 = { f2bf(acc[m][n][0]+bias_n[n]), f2bf(acc[m][n][1]+bias_n[n]),
                         f2bf(acc[m][n][2]+bias_n[n]), f2bf(acc[m][n][3]+bias_n[n]) };
            *(u16x4*)&SHT[col_loc*136 + tok_l] = v4;
          }
        }
      }
      __syncthreads();
      int d_loc = t>>2, qtr = t&3;
      int d = pass*64 + d_loc;
      int tok0 = R + qtr*32;
      long base;
      if (img) base = ((long)hd*128 + d)*2048 + tok0;
      else { int t2 = tok0 - rows_img; int b_ = t2>>9, s_ = t2&511;
             base = ((long)(b_*24+hd)*128 + d)*512 + s_; }
      #pragma unroll
      for (int k2=0;k2<4;k2++)
        *(u16x8*)(Vd + base + k2*8) = *(const u16x8*)&SHT[d_loc*136 + qtr*32 + k2*8];
    }
    return;
  }

  // ---- fused RMSNorm + RoPE epilogue (Q/K) ----
  float part[4][4];
  #pragma unroll
  for (int m=0;m<4;m++)
    #pragma unroll
    for (int r=0;r<4;r++){
      float s_ = 0.f;
      #pragma unroll
      for (int n=0;n<4;n++){ float v = acc[m][n][r] + bias_n[n]; s_ += v*v; }
      part[m][r] = s_;
    }
  #pragma unroll
  for (int m=0;m<4;m++)
    #pragma unroll
    for (int r=0;r<4;r++){
      part[m][r] += __shfl_xor(part[m][r], 1);
      part[m][r] += __shfl_xor(part[m][r], 2);
      part[m][r] += __shfl_xor(part[m][r], 4);
      part[m][r] += __shfl_xor(part[m][r], 8);
    }
  __syncthreads();                                   // staging reads done; reuse SH
  float* rs = (float*)SH;                            // [2 wc][2 wr][64 row]
  if (li == 0){
    #pragma unroll
    for (int m=0;m<4;m++)
      #pragma unroll
      for (int r=0;r<4;r++)
        rs[(wc*2+wr)*64 + m*16 + g*4 + r] = part[m][r];
  }
  __syncthreads();
  float fac[4][4];
  #pragma unroll
  for (int m=0;m<4;m++)
    #pragma unroll
    for (int r=0;r<4;r++){
      int idx = m*16 + g*4 + r;
      float tot = rs[(0*2+wr)*64 + idx] + rs[(1*2+wr)*64 + idx];
      fac[m][r] = rsqrtf(tot*(1.0f/128.0f) + 1e-6f);
    }

  const float* nw = (sec==0) ? (img ? nq_ : naq_) : (img ? nk_ : nak_);
  const float qs = (sec==0) ? (float)(0.08838834764831845 * 1.4426950408889634) : 1.0f;
  float nw_n[4];
  #pragma unroll
  for (int n=0;n<4;n++) nw_n[n] = nw[wc*64 + n*16 + li];

  unsigned short* Kd = img ? Kdi : Kde;

  #pragma unroll
  for (int m=0;m<4;m++){
    #pragma unroll
    for (int r=0;r<4;r++){
      int row_l = wr*64 + m*16 + g*4 + r;
      int t_row = R + row_l;
      int b_, s_, p_;
      if (img){ b_ = t_row>>10; s_ = t_row&1023; p_ = 512+s_; }
      else { int t2 = t_row - rows_img; b_ = t2>>9; s_ = t2&511; p_ = s_; }
      long didx;
      if (sec==0) didx = (long)(b_*24+hd)*1536 + (img ? 512+s_ : s_);
      else        didx = img ? ((long)hd*2048 + t_row) : ((long)(b_*24+hd)*512 + s_);
      const float* crow = cs + (long)p_*128;
      const float* srow = sn + (long)p_*128;
      unsigned short* drow = ((sec==0)?Qd:Kd) + didx*128;
      #pragma unroll
      for (int n=0;n<4;n++){
        int cl = wc*64 + n*16 + li;
        float x = (acc[m][n][r] + bias_n[n]) * fac[m][r] * nw_n[n];
        float xo = __shfl_xor(x, 1);
        float o_ = x*crow[cl] + ((l&1) ? xo*srow[cl] : -xo*srow[cl]);
        drow[cl] = f2bf(o_*qs);
      }
    }
  }
}

// ---------------- fused output GEMM (block-diagonal over rows) ----------------
// XCD swizzle 2D (2 x-groups, 4 y-groups): kept from round 13 (net winner).
__global__ __launch_bounds__(256) void k_gemmO(
    const unsigned short* __restrict__ X, const unsigned short* __restrict__ Wf,
    float* __restrict__ out, const float* __restrict__ bo, const float* __restrict__ bao)
{
  const int K = 3072;
  __shared__ unsigned short As[2][4096];
  __shared__ unsigned short Bs[2][4096];
  const int t = threadIdx.x, w = t>>6, l = t&63;
  // decode: grid (24,24); hw XCD = wid%8 = xg + 2*yg
  unsigned wid = blockIdx.x + 24u*blockIdx.y;
  unsigned xc = wid & 7, ii = wid >> 3;              // ii in [0,72)
  unsigned xg = xc & 1, yg = xc >> 1;
  int bx = (int)(xg*12 + ii%12);
  int by = (int)(yg*6 + ii/12);
  const bool enc = bx >= 16;
  const unsigned short* Wp = Wf + (enc ? 9437184 : 0);
  const float* bias = enc ? bao : bo;
  const int R = bx*128, C = by*128;
  long xbase, obase;
  if (!enc){ xbase = (long)(R>>10)*1536 + 512 + (R&1023); obase = (long)R*3072; }
  else { int Rp = R-2048; xbase = (long)(Rp>>9)*1536 + (Rp&511); obase = 6291456 + (long)Rp*3072; }
  const int wr = w>>1, wc = w&1;
  f32x4 acc[4][4] = {};

  auto stage = [&](int buf, int kt){
    const int k0 = kt*32;
    #pragma unroll
    for (int c=0;c<2;c++){
      int row = c*64 + (t>>2);
      int scol = ((t&3)<<3) ^ ((row&3)<<3) ^ (((row>>3)&1)<<4);
      gll16(X + (xbase+row)*K + k0 + scol, &As[buf][c*2048 + w*512]);
      gll16(Wp + (long)(C+row)*K + k0 + scol, &Bs[buf][c*2048 + w*512]);
    }
  };

  stage(0,0);
  int buf = 0;
  for (int kt=0; kt<96; kt++){
    __syncthreads();
    if (kt+1 < 96) stage(buf^1, kt+1);
    bf16x8 a[4], b[4];
    #pragma unroll
    for (int m=0;m<4;m++){
      int ar = wr*64 + m*16 + (l&15);
      int ac = ((l>>4)<<3) ^ ((ar&3)<<3) ^ (((ar>>3)&1)<<4);
      a[m] = *(const bf16x8*)&As[buf][ar*32 + ac];
      int br = wc*64 + m*16 + (l&15);
      int bc2 = ((l>>4)<<3) ^ ((br&3)<<3) ^ (((br>>3)&1)<<4);
      b[m] = *(const bf16x8*)&Bs[buf][br*32 + bc2];
    }
    #pragma unroll
    for (int m=0;m<4;m++)
      #pragma unroll
      for (int n=0;n<4;n++)
        acc[m][n] = __builtin_amdgcn_mfma_f32_16x16x32_bf16(a[m], b[n], acc[m][n], 0,0,0);
    buf ^= 1;
  }

  #pragma unroll
  for (int m=0;m<4;m++){
    int rl = wr*64 + m*16 + ((l>>4)<<2);
    #pragma unroll
    for (int n=0;n<4;n++){
      int col = C + wc*64 + n*16 + (l&15);
      float bvv = bias[col];
      #pragma unroll
      for (int r=0;r<4;r++)
        out[obase + (long)(rl+r)*3072 + col] = acc[m][n][r] + bvv;
    }
  }
}

// ---------------- flash attention (proven schedule + h-chunked XCD swizzle) ----------------
__global__ __launch_bounds__(256) void k_attn(
    const unsigned short* __restrict__ Q,
    const unsigned short* __restrict__ Ke, const unsigned short* __restrict__ Ki,
    const unsigned short* __restrict__ Ve, const unsigned short* __restrict__ Vi,
    unsigned short* __restrict__ AO)
{
  __shared__ unsigned short Ks[8192];          // [64 kv][128 d], XOR-swizzled
  __shared__ unsigned short Vs[8192];          // [128 d][64 kv], XOR-swizzled
  __shared__ unsigned short Ps[4][1408];       // per-wave P tile [16 q][88 k-pad]
  const int t = threadIdx.x, w = t>>6, l = t&63;
  // decode: grid (24,24,2); hw XCD = wid%8 owns heads [3*xc, 3*xc+3)
  unsigned wid = blockIdx.x + 24u*blockIdx.y + 576u*blockIdx.z;
  unsigned xc = wid & 7, ii = wid >> 3;              // ii in [0,144)
  int h = (int)(xc*3 + ii/48);
  unsigned rem = ii % 48;
  int b = (int)(rem/24);
  int qx = (int)(rem%24);
  const int bh = b*24 + h;
  const int q0 = qx*64 + w*16;
  const int g = l>>4;

  auto stageK = [&](int jt){
    const unsigned short* ksrc = (jt < 8) ? Ke + ((long)bh*512 + jt*64)*128
                                          : Ki + ((long)h*2048 + (jt-8)*64)*128;
    #pragma unroll
    for (int c=0;c<4;c++){
      int row = c*16 + (t>>4);
      int col = ((t&15)<<3) ^ ((row&7)<<3);
      gll16(ksrc + row*128 + col, &Ks[c*2048 + w*512]);
    }
  };
  auto stageV = [&](int jt){
    const unsigned short* vsrc; long vstr;
    if (jt < 8){ vsrc = Ve + (long)bh*65536 + jt*64; vstr = 512; }
    else { vsrc = Vi + (long)h*262144 + (jt-8)*64; vstr = 2048; }
    #pragma unroll
    for (int c=0;c<4;c++){
      int row = c*32 + (t>>3);
      int col = ((t&7)<<3) ^ ((row&7)<<3);
      gll16(vsrc + (long)row*vstr + col, &Vs[c*2048 + w*512]);
    }
  };

  bf16x8 qf[4];
  {
    const unsigned short* qp = Q + ((long)bh*1536 + q0 + (l&15))*128 + (g<<3);
    #pragma unroll
    for (int kc=0;kc<4;kc++) qf[kc] = *(const bf16x8*)(qp + kc*32);
  }
  f32x4 o[8] = {};
  float mx = -1e30f;
  float ls = 0.f;            // per-lane partial sum over own (q, k-slice)

  stageK(0);
  for (int jt=0; jt<40; jt++){
    __syncthreads();                 // K(jt) landed; all waves past PV(jt-1)
    stageV(jt);                      // covered by QK + softmax below

    // S^T tile: sf[ct][r] = S[q = q0 + (l&15)][k = ct*16 + g*4 + r]
    f32x4 sf[4];
    __builtin_amdgcn_s_setprio(1);
    #pragma unroll
    for (int ct=0;ct<4;ct++){
      f32x4 s = {};
      #pragma unroll
      for (int kc=0;kc<4;kc++){
        int krow = ct*16 + (l&15);
        int kcol = (kc*32 + (g<<3)) ^ ((krow&7)<<3);
        bf16x8 kb = *(const bf16x8*)&Ks[krow*128 + kcol];
        s = __builtin_amdgcn_mfma_f32_16x16x32_bf16(kb, qf[kc], s, 0,0,0);  // SWAPPED
      }
      sf[ct] = s;
    }
    __builtin_amdgcn_s_setprio(0);

    // per-lane slice max (own q); defer-max with THR=8 (log2 domain)
    float pm = sf[0][0];
    #pragma unroll
    for (int ct=0;ct<4;ct++)
      #pragma unroll
      for (int r=0;r<4;r++) pm = fmaxf(pm, sf[ct][r]);
    if (!__all(pm <= mx + 8.0f)){
      float tmax = pm;
      tmax = fmaxf(tmax, __shfl_xor(tmax, 16));
      tmax = fmaxf(tmax, __shfl_xor(tmax, 32));     // full-row max for own q
      float mn = fmaxf(mx, tmax);
      float al = exp2f(mx - mn);
      mx = mn;
      ls *= al;
      #pragma unroll
      for (int r=0;r<4;r++){
        float alo = __shfl(al, (l&48) | ((g<<2)+r));  // factor for o-row q' = 4g+r
        #pragma unroll
        for (int f=0;f<8;f++) o[f][r] *= alo;
      }
    }
    // P = exp2(S - mx), pack pairs, write b64; accumulate per-lane ls
    #pragma unroll
    for (int ct=0;ct<4;ct++){
      float p0 = exp2f(sf[ct][0]-mx), p1 = exp2f(sf[ct][1]-mx);
      float p2 = exp2f(sf[ct][2]-mx), p3 = exp2f(sf[ct][3]-mx);
      ls += (p0+p1)+(p2+p3);
      uint2v pk = { cvtpk(p0,p1), cvtpk(p2,p3) };
      *(uint2v*)&Ps[w][(l&15)*88 + ct*16 + (g<<2)] = pk;
    }
    __syncthreads();                 // V(jt) landed; all waves done reading Ks

    if (jt+1 < 40) stageK(jt+1);     // overwrites Ks; covered by PV below

    bf16x8 pa[2];
    #pragma unroll
    for (int kc=0;kc<2;kc++)
      pa[kc] = *(const bf16x8*)&Ps[w][(l&15)*88 + kc*32 + (g<<3)];
    __builtin_amdgcn_s_setprio(1);
    #pragma unroll
    for (int f=0;f<8;f++){
      #pragma unroll
      for (int kc=0;kc<2;kc++){
        int vrow = f*16 + (l&15);
        int vcol = (kc*32 + (g<<3)) ^ ((vrow&7)<<3);
        bf16x8 vb = *(const bf16x8*)&Vs[vrow*64 + vcol];
        o[f] = __builtin_amdgcn_mfma_f32_16x16x32_bf16(pa[kc], vb, o[f], 0,0,0);
      }
    }
    __builtin_amdgcn_s_setprio(0);
  }

  // finalize: full row-sum for own q, then fetch for o-rows q' = 4g+r
  ls += __shfl_xor(ls, 16);
  ls += __shfl_xor(ls, 32);
  #pragma unroll
  for (int r=0;r<4;r++){
    float lso = __shfl(ls, (l&48) | ((g<<2)+r));
    float inv = 1.0f/lso;
    int qrow = q0 + (g<<2) + r;
    #pragma unroll
    for (int f=0;f<8;f++){
      AO[((long)b*1536 + qrow)*3072 + h*128 + f*16 + (l&15)] = f2bf(o[f][r]*inv);
    }
  }
}

// ---------------- host launch ----------------
extern "C" void kernel_launch(void* const* d_in, const int* in_sizes, int n_in,
                              void* d_out, int out_size, void* d_ws, size_t ws_size,
                              hipStream_t stream)
{
  const float* hs  = (const float*)d_in[0];
  const float* ehs = (const float*)d_in[1];
  const float* rc  = (const float*)d_in[2];
  const float* rs_ = (const float*)d_in[3];
  const float* wq = (const float*)d_in[4];  const float* bq = (const float*)d_in[5];
  const float* wk = (const float*)d_in[6];  const float* bk = (const float*)d_in[7];
  const float* wv = (const float*)d_in[8];  const float* bv = (const float*)d_in[9];
  const float* waq= (const float*)d_in[10]; const float* baq= (const float*)d_in[11];
  const float* wak= (const float*)d_in[12]; const float* bak= (const float*)d_in[13];
  const float* wav= (const float*)d_in[14]; const float* bav= (const float*)d_in[15];
  const float* wo = (const float*)d_in[16]; const float* bo = (const float*)d_in[17];
  const float* wao= (const float*)d_in[18]; const float* bao= (const float*)d_in[19];
  const float* nq = (const float*)d_in[20]; const float* nk = (const float*)d_in[21];
  const float* naq= (const float*)d_in[22]; const float* nak= (const float*)d_in[23];

  char* p = (char*)d_ws;
  auto alloc = [&](size_t bytes){ char* r = p; p += bytes; return r; };

  if (ws_size >= (size_t)226492416){
    // ---------- main path (226.5 MB; 245.4 proven available in round 4) ----------
    unsigned short* Xh = (unsigned short*)alloc(12582912);  // [2048][3072]
    unsigned short* Xe = (unsigned short*)alloc(6291456);   // [1024][3072] (contiguous after Xh)
    unsigned short* Wb = (unsigned short*)alloc(150994944); // 8 weight slots bf16
    unsigned short* Qb = (unsigned short*)alloc(18874368);  // Q [2][24][1536][128]
    unsigned short* Ke = (unsigned short*)alloc(6291456);   // Kenc [2][24][512][128]
    unsigned short* Ki = (unsigned short*)alloc(12582912);  // Kimg [24][2048][128]
    unsigned short* Ve = (unsigned short*)alloc(6291456);   // Vtenc [2][24][128][512]
    unsigned short* Vi = (unsigned short*)alloc(12582912);  // Vtimg [24][128][2048]
    unsigned short* AO = Xh;                                // aliases Xh+Xe (dead by attn)
    (void)Xe;

    k_castAll<<<82944,256,0,stream>>>(wq, wk, wv, waq, wak, wav, wo, wao, hs, ehs, Wb, Xh);

    // merged img+enc QKV GEMM (rows 0..2047 img, 2048..3071 enc)
    k_gemmP<<<dim3(24,72),256,0,stream>>>(Xh, Wb, Wb + (long)3*9437184,
                                          bq, bk, bv, baq, bak, bav,
                                          nq, nk, naq, nak, rc, rs_,
                                          Qb, Ki, Ke, Vi, Ve, 2048);

    k_attn<<<dim3(24,24,2),256,0,stream>>>(Qb, Ke, Ki, Ve, Vi, AO);

    k_gemmO<<<dim3(24,24),256,0,stream>>>(AO, Wb + (long)6*9437184, (float*)d_out, bo, bao);
  } else {
    // ---------- fallback path (132.1 MB): 3 weight slots, groups sequential ----------
    unsigned short* Xh = (unsigned short*)alloc(12582912);
    unsigned short* Xe = (unsigned short*)alloc(6291456);
    unsigned short* Wb = (unsigned short*)alloc(56623104);  // 3 slots
    unsigned short* Qb = (unsigned short*)alloc(18874368);
    unsigned short* Ke = (unsigned short*)alloc(6291456);
    unsigned short* Ki = (unsigned short*)alloc(12582912);
    unsigned short* Ve = (unsigned short*)alloc(6291456);
    unsigned short* Vi = (unsigned short*)alloc(12582912);
    unsigned short* AO = Xh;

    k_castX2<<<9216,256,0,stream>>>(hs, ehs, Xh);

    k_cast<<<9216,256,0,stream>>>(wq, Wb, 2359296);
    k_cast<<<9216,256,0,stream>>>(wk, Wb + 9437184, 2359296);
    k_cast<<<9216,256,0,stream>>>(wv, Wb + 18874368, 2359296);
    k_gemmP<<<dim3(16,72),256,0,stream>>>(Xh, Wb, Wb,
                                          bq, bk, bv, bq, bk, bv,
                                          nq, nk, nq, nk, rc, rs_,
                                          Qb, Ki, Ke, Vi, Ve, 1<<28);

    k_cast<<<9216,256,0,stream>>>(waq, Wb, 2359296);
    k_cast<<<9216,256,0,stream>>>(wak, Wb + 9437184, 2359296);
    k_cast<<<9216,256,0,stream>>>(wav, Wb + 18874368, 2359296);
    k_gemmP<<<dim3(8,72),256,0,stream>>>(Xe, Wb, Wb,
                                         baq, bak, bav, baq, bak, bav,
                                         naq, nak, naq, nak, rc, rs_,
                                         Qb, Ki, Ke, Vi, Ve, 0);

    k_attn<<<dim3(24,24,2),256,0,stream>>>(Qb, Ke, Ki, Ve, Vi, AO);

    k_castW2<<<18432,256,0,stream>>>(wo, wao, Wb);
    k_gemmO<<<dim3(24,24),256,0,stream>>>(AO, Wb, (float*)d_out, bo, bao);
  }
}